// Round 2
// baseline (4462.713 us; speedup 1.0000x reference)
//
#include <hip/hip_runtime.h>
#include <hip/hip_cooperative_groups.h>
#include <cfloat>
#include <climits>
#include <cstdint>

namespace cg = cooperative_groups;

#define HH 1024
#define WW 2048
#define NPIX (HH * WW)
#define NWORD (NPIX / 64)
#define TPB 256
#define MAXBLK 1024

// ---- workspace layout (bytes). total ~820 KB ----
#define OFF_UNCL ((size_t)0)
#define OFF_P1   (OFF_UNCL + (size_t)NWORD * 8)
#define OFF_P2   (OFF_P1   + (size_t)NWORD * 8)
#define OFF_AV   (OFF_P2   + (size_t)NWORD * 8)
#define OFF_AI   (OFF_AV + (size_t)MAXBLK * 4)
#define OFF_AS   (OFF_AI + (size_t)MAXBLK * 4)
#define OFF_BV   (OFF_AS + (size_t)MAXBLK * 4)
#define OFF_BI   (OFF_BV + (size_t)MAXBLK * 4)
#define OFF_BS   (OFF_BI + (size_t)MAXBLK * 4)
#define OFF_CS   (OFF_BS + (size_t)MAXBLK * 4)
#define OFF_CS2  (OFF_CS + (size_t)MAXBLK * 4)
#define OFF_SIZES (OFF_CS2 + (size_t)MAXBLK * 4)
#define OFF_NOW  (OFF_SIZES + (size_t)256 * 4)

// seed_map = softmax(pred[5:7], axis=0)[1], replicated op-for-op (max-subtract)
__device__ __forceinline__ float compute_sm(const float* __restrict__ pred, int i) {
  float a = pred[(size_t)5 * NPIX + i];
  float b = pred[(size_t)6 * NPIX + i];
  float m = fmaxf(a, b);
  float ea = expf(a - m);
  float eb = expf(b - m);
  return eb / (ea + eb);
}

// emb = tanh(pred[:2]) + xym ; xym from linspace: c*(2/2047), r*(1/1023)
__device__ __forceinline__ void compute_emb(const float* __restrict__ pred, int i,
                                            float& ex, float& ey) {
#pragma clang fp contract(off)
  int r = i >> 11;
  int c = i & (WW - 1);
  float xm = (float)c * (2.0f / 2047.0f);
  float ym = (float)r * (1.0f / 1023.0f);
  ex = tanhf(pred[i]) + xm;
  ey = tanhf(pred[(size_t)NPIX + i]) + ym;
}

// dist = exp(-((dx*dx)*sx + (dy*dy)*sy)) > 0.5, exact reference association
__device__ __forceinline__ bool prop_test(float ex, float ey, float cx, float cy,
                                          float sx, float sy) {
#pragma clang fp contract(off)
  float dx = ex - cx;
  float dy = ey - cy;
  float t0 = dx * dx; t0 = t0 * sx;
  float t1 = dy * dy; t1 = t1 * sy;
  float d = expf(-(t0 + t1));
  return d > 0.5f;
}

// block-level argmax(val, first index) + two int sums. Deterministic.
__device__ __forceinline__ void block_reduce(float& v, int& idx, int& s1, int& s2,
                                             float* lV, int* lI, int* lS, int* lS2) {
  int tid = threadIdx.x;
  lV[tid] = v; lI[tid] = idx; lS[tid] = s1; lS2[tid] = s2;
  __syncthreads();
  for (int off = TPB >> 1; off > 0; off >>= 1) {
    if (tid < off) {
      float vo = lV[tid + off]; int io = lI[tid + off];
      if (vo > lV[tid] || (vo == lV[tid] && io < lI[tid])) { lV[tid] = vo; lI[tid] = io; }
      lS[tid] += lS[tid + off];
      lS2[tid] += lS2[tid + off];
    }
    __syncthreads();
  }
  v = lV[0]; idx = lI[0]; s1 = lS[0]; s2 = lS2[0];
  __syncthreads();
}

// combine per-block partials redundantly in every block (saves a grid sync)
__device__ __forceinline__ void final_reduce_vis(const float* gV, const int* gI, const int* gS,
                                                 int nblk, float& v, int& idx, int& s,
                                                 float* lV, int* lI, int* lS, int* lS2) {
  float bv = -FLT_MAX; int bi = INT_MAX; int bs = 0; int d = 0;
  for (int b = threadIdx.x; b < nblk; b += TPB) {
    float vv = gV[b]; int ii = gI[b]; bs += gS[b];
    if (vv > bv || (vv == bv && ii < bi)) { bv = vv; bi = ii; }
  }
  block_reduce(bv, bi, bs, d, lV, lI, lS, lS2);
  v = bv; idx = bi; s = bs;
}

__device__ __forceinline__ void final_reduce_ss(const int* gS, const int* gS2, int nblk,
                                                int& s1, int& s2,
                                                float* lV, int* lI, int* lS, int* lS2) {
  float bv = -FLT_MAX; int bi = INT_MAX; int bs = 0; int bs2 = 0;
  for (int b = threadIdx.x; b < nblk; b += TPB) { bs += gS[b]; bs2 += gS2[b]; }
  block_reduce(bv, bi, bs, bs2, lV, lI, lS, lS2);
  s1 = bs; s2 = bs2;
}

__global__ void precompute_kernel(const float* __restrict__ pred, int* __restrict__ out,
                                  char* __restrict__ ws) {
  uint64_t* UNCLW = (uint64_t*)(ws + OFF_UNCL);
  int* SIZES = (int*)(ws + OFF_SIZES);
  int* NOW = (int*)(ws + OFF_NOW);
  int gid = blockIdx.x * blockDim.x + threadIdx.x;
  int stride = gridDim.x * blockDim.x;   // multiple of 64
  for (int i = gid; i < NPIX; i += stride) {
    float smv = compute_sm(pred, i);
    bool m = smv > 0.5f;                 // mask = seed_map > MIN_SEED_THRESH
    unsigned long long bal = __ballot(m);
    if ((threadIdx.x & 63) == 0) UNCLW[i >> 6] = bal;
    out[i] = 0;
  }
  if (gid < 256) { SIZES[gid] = 0; NOW[gid] = 0; }
}

__global__ __launch_bounds__(TPB, 4) void cluster_kernel(const float* __restrict__ pred,
                                                         int* __restrict__ out,
                                                         char* __restrict__ ws, int nblk) {
  cg::grid_group grid = cg::this_grid();
  uint64_t* UNCLW = (uint64_t*)(ws + OFF_UNCL);
  uint64_t* P1W = (uint64_t*)(ws + OFF_P1);
  uint64_t* P2W = (uint64_t*)(ws + OFF_P2);
  float* aV = (float*)(ws + OFF_AV); int* aI = (int*)(ws + OFF_AI); int* aS = (int*)(ws + OFF_AS);
  float* bV = (float*)(ws + OFF_BV); int* bI = (int*)(ws + OFF_BI); int* bS = (int*)(ws + OFF_BS);
  int* cS = (int*)(ws + OFF_CS); int* cS2 = (int*)(ws + OFF_CS2);
  int* SIZES = (int*)(ws + OFF_SIZES);
  int* NOW = (int*)(ws + OFF_NOW);

  const int tid = threadIdx.x;
  const int gid = blockIdx.x * TPB + tid;
  const int stride = nblk * TPB;

  __shared__ float lV[TPB];
  __shared__ int lI[TPB];
  __shared__ int lS[TPB];
  __shared__ int lS2[TPB];
  __shared__ int lbin[256];

  // ---- Pass A0: sum(uncl), argmax(seed_map*uncl) ----
  float bv = -FLT_MAX; int bi = INT_MAX; int s = 0; int dum = 0;
  for (int i = gid; i < NPIX; i += stride) {
    if ((UNCLW[i >> 6] >> (i & 63)) & 1ull) {
      s++;
      float v = compute_sm(pred, i);
      if (v > bv || (v == bv && i < bi)) { bv = v; bi = i; }
    }
  }
  block_reduce(bv, bi, s, dum, lV, lI, lS, lS2);
  if (tid == 0) { aV[blockIdx.x] = bv; aI[blockIdx.x] = bi; aS[blockIdx.x] = s; }
  grid.sync();
  float val1; int seed1; int Sall;
  final_reduce_vis(aV, aI, aS, nblk, val1, seed1, Sall, lV, lI, lS, lS2);

  int count = 1, it = 0;
  while (Sall > 160 && count < 200 && it < 2000) {
    if (val1 < 0.5f) break;   // 'stop' branch freezes state -> exit

    float cx1, cy1; compute_emb(pred, seed1, cx1, cy1);
    float sx1 = expf(pred[(size_t)2 * NPIX + seed1] * 10.0f);
    float sy1 = expf(pred[(size_t)3 * NPIX + seed1] * 10.0f);

    // ---- Pass B: prop1 bits, cnt1, seed2 = argmax(sigmoid(seed_val) | prop1) ----
    float bvB = -FLT_MAX; int biB = INT_MAX; int c1 = 0; int dumB = 0;
    for (int i = gid; i < NPIX; i += stride) {
      float smv = compute_sm(pred, i);
      float ex, ey; compute_emb(pred, i, ex, ey);
      bool p = prop_test(ex, ey, cx1, cy1, sx1, sy1) && (smv > 0.5f);
      unsigned long long bal = __ballot(p);
      if ((tid & 63) == 0) P1W[i >> 6] = bal;
      if (p) {
        c1++;
        // reference argmaxes sigmoid(seed_val); replicate the rounding so
        // first-index tie-breaks land on the same pixel
        float v = 1.0f / (1.0f + expf(-pred[(size_t)4 * NPIX + i]));
        if (v > bvB || (v == bvB && i < biB)) { bvB = v; biB = i; }
      }
    }
    block_reduce(bvB, biB, c1, dumB, lV, lI, lS, lS2);
    if (tid == 0) { bV[blockIdx.x] = bvB; bI[blockIdx.x] = biB; bS[blockIdx.x] = c1; }
    grid.sync();
    float svmax; int seed2; int cnt1;
    final_reduce_vis(bV, bI, bS, nblk, svmax, seed2, cnt1, lV, lI, lS, lS2);
    bool big1 = cnt1 > 160;

    float cx2, cy2; compute_emb(pred, seed2, cx2, cy2);
    float sx2 = expf(pred[(size_t)2 * NPIX + seed2] * 10.0f);
    float sy2 = expf(pred[(size_t)3 * NPIX + seed2] * 10.0f);

    // ---- Pass C: prop2 bits, cnt2, overlap with uncl ----
    int c2 = 0, ov = 0;
    float fdum = -FLT_MAX; int idum = INT_MAX;
    for (int i = gid; i < NPIX; i += stride) {
      float smv = compute_sm(pred, i);
      float ex, ey; compute_emb(pred, i, ex, ey);
      bool p = prop_test(ex, ey, cx2, cy2, sx2, sy2) && (smv > 0.5f);
      unsigned long long bal = __ballot(p);
      if ((tid & 63) == 0) P2W[i >> 6] = bal;
      if (p) {
        c2++;
        if ((UNCLW[i >> 6] >> (i & 63)) & 1ull) ov++;
      }
    }
    block_reduce(fdum, idum, c2, ov, lV, lI, lS, lS2);
    if (tid == 0) { cS[blockIdx.x] = c2; cS2[blockIdx.x] = ov; }
    grid.sync();
    int cnt2, ovl;
    final_reduce_ss(cS, cS2, nblk, cnt2, ovl, lV, lI, lS, lS2);

    // corrections: reference clears uncl at seed1 (always) and seed2 (if big1)
    // BEFORE the overlap sum; we folded the clears into Pass D, so subtract here.
    // (read UNCLW/P2W now, BEFORE anyone starts rewriting UNCLW in Pass D)
    if (((P2W[seed1 >> 6] >> (seed1 & 63)) & 1ull) &&
        ((UNCLW[seed1 >> 6] >> (seed1 & 63)) & 1ull)) ovl--;
    if (big1 && seed2 != seed1 &&
        ((P2W[seed2 >> 6] >> (seed2 & 63)) & 1ull) &&
        ((UNCLW[seed2 >> 6] >> (seed2 & 63)) & 1ull)) ovl--;

    // race fix: ensure every block has finished reading UNCLW for the
    // corrections above before any block's Pass D rewrites it.
    grid.sync();

    bool big2 = cnt2 > 160;
    int den = cnt2 > 1 ? cnt2 : 1;
    float ratio = (float)ovl / (float)den;
    bool accept = big1 && big2 && (ratio > 0.5f);
    if (accept && gid == 0) SIZES[count] = cnt2;

    // ---- Pass D (update) fused with next Pass A ----
    float bvA = -FLT_MAX; int biA = INT_MAX; int sA = 0; int dumA = 0;
    for (int i = gid; i < NPIX; i += stride) {
      int w = i >> 6, b = i & 63;
      bool p1 = (P1W[w] >> b) & 1ull;
      bool p2 = (P2W[w] >> b) & 1ull;
      bool u = (UNCLW[w] >> b) & 1ull;
      bool fp = big1 ? p2 : p1;
      bool nu = u && !(fp || i == seed1 || (big1 && i == seed2));
      unsigned long long bal = __ballot(nu);
      if ((tid & 63) == 0) UNCLW[w] = bal;
      if (accept && p2) out[i] = count;
      if (nu) {
        sA++;
        float v = compute_sm(pred, i);
        if (v > bvA || (v == bvA && i < biA)) { bvA = v; biA = i; }
      }
    }
    block_reduce(bvA, biA, sA, dumA, lV, lI, lS, lS2);
    if (tid == 0) { aV[blockIdx.x] = bvA; aI[blockIdx.x] = biA; aS[blockIdx.x] = sA; }
    if (accept) count++;
    it++;
    grid.sync();
    final_reduce_vis(aV, aI, aS, nblk, val1, seed1, Sall, lV, lI, lS, lS2);
  }

  // ---- post-filter: bincount(now), remove small/overwritten ids ----
  lbin[tid] = 0;
  __syncthreads();
  for (int i = gid; i < NPIX; i += stride) {
    int id = out[i];
    atomicAdd(&lbin[id], 1);
  }
  __syncthreads();
  if (lbin[tid] > 0) atomicAdd(&NOW[tid], lbin[tid]);
  grid.sync();
  for (int i = gid; i < NPIX; i += stride) {
    int id = out[i];
    if (id > 0) {
      int n = NOW[id];
      int sz = SIZES[id];
      bool rm = (n != sz) && ((n < 480) || ((float)n < 0.5f * (float)sz));
      if (rm) out[i] = 0;
    }
  }
}

extern "C" void kernel_launch(void* const* d_in, const int* in_sizes, int n_in,
                              void* d_out, int out_size, void* d_ws, size_t ws_size,
                              hipStream_t stream) {
  const float* pred = (const float*)d_in[0];
  int* out = (int*)d_out;
  char* ws = (char*)d_ws;

  hipLaunchKernelGGL(precompute_kernel, dim3(2048), dim3(TPB), 0, stream, pred, out, ws);

  int nblk = MAXBLK;
  int maxPerCU = 0;
  if (hipOccupancyMaxActiveBlocksPerMultiprocessor(&maxPerCU, (const void*)cluster_kernel,
                                                   TPB, 0) == hipSuccess && maxPerCU > 0) {
    int dev = 0;
    hipGetDevice(&dev);
    int numCU = 0;
    if (hipDeviceGetAttribute(&numCU, hipDeviceAttributeMultiprocessorCount, dev) == hipSuccess &&
        numCU > 0) {
      long long cap = (long long)maxPerCU * numCU;
      if (cap < nblk) nblk = (int)cap;
    }
  }
  if (nblk < 1) nblk = 1;
  void* args[] = {(void*)&pred, (void*)&out, (void*)&ws, (void*)&nblk};
  hipLaunchCooperativeKernel((void*)cluster_kernel, dim3(nblk), dim3(TPB), args, 0, stream);
}

// Round 3
// 3895.753 us; speedup vs baseline: 1.1455x; 1.1455x over previous
//
#include <hip/hip_runtime.h>
#include <cfloat>
#include <climits>
#include <cstdint>

#define HH 1024
#define WW 2048
#define NPIX (HH * WW)
#define NWORD (NPIX / 64)
#define TPB 256
#define MAXBLK 2048
#define NGRP 64
#define UNROLL 4

// ---- workspace layout (bytes) ----
#define OFF_MASK ((size_t)0x0)
#define OFF_UNCL ((size_t)0x40000)
#define OFF_P1   ((size_t)0x80000)
#define OFF_P2   ((size_t)0xC0000)
#define OFF_AV   ((size_t)0x100000)
#define OFF_AI   ((size_t)0x102000)
#define OFF_AS   ((size_t)0x104000)
#define OFF_AS2  ((size_t)0x106000)
#define OFF_CTL  ((size_t)0x108000)   // 4096 ints
#define OFF_SM   ((size_t)0x200000)   // 8 MB
#define OFF_SV   ((size_t)0xA00000)   // 8 MB
#define OFF_EXY  ((size_t)0x1200000)  // 16 MB
#define FAT_NEED ((size_t)0x2200000)  // 34 MB

// CTL int indices
#define CTL_ROOT 2048
#define CTL_GEN  2080
#define CTL_SCAL 2112   // 64 slots
#define CTL_SIZ  2304   // 256
#define CTL_NOW  2560   // 256

// agent-scope atomic helpers (bypass local caches, coherent across XCDs)
__device__ __forceinline__ int al(const int* p) {
  return __hip_atomic_load((int*)p, __ATOMIC_RELAXED, __HIP_MEMORY_SCOPE_AGENT);
}
__device__ __forceinline__ void as_(int* p, int v) {
  __hip_atomic_store(p, v, __ATOMIC_RELAXED, __HIP_MEMORY_SCOPE_AGENT);
}
__device__ __forceinline__ float alf(const int* p) { return __int_as_float(al(p)); }
__device__ __forceinline__ void asf(int* p, float v) { as_(p, __float_as_int(v)); }

// seed_map = softmax(pred[5:7], axis=0)[1], replicated op-for-op (max-subtract)
__device__ __forceinline__ float compute_sm(const float* __restrict__ pred, int i) {
  float a = pred[(size_t)5 * NPIX + i];
  float b = pred[(size_t)6 * NPIX + i];
  float m = fmaxf(a, b);
  float ea = expf(a - m);
  float eb = expf(b - m);
  return eb / (ea + eb);
}

// emb = tanh(pred[:2]) + xym ; xym from linspace: c*(2/2047), r*(1/1023)
__device__ __forceinline__ void compute_emb(const float* __restrict__ pred, int i,
                                            float& ex, float& ey) {
#pragma clang fp contract(off)
  int r = i >> 11;
  int c = i & (WW - 1);
  float xm = (float)c * (2.0f / 2047.0f);
  float ym = (float)r * (1.0f / 1023.0f);
  ex = tanhf(pred[i]) + xm;
  ey = tanhf(pred[(size_t)NPIX + i]) + ym;
}

// dist = exp(-((dx*dx)*sx + (dy*dy)*sy)) > 0.5, exact reference association
__device__ __forceinline__ bool prop_test(float ex, float ey, float cx, float cy,
                                          float sx, float sy) {
#pragma clang fp contract(off)
  float dx = ex - cx;
  float dy = ey - cy;
  float t0 = dx * dx; t0 = t0 * sx;
  float t1 = dy * dy; t1 = t1 * sy;
  float d = expf(-(t0 + t1));
  return d > 0.5f;
}

template <bool FAT>
__device__ __forceinline__ void get_e(const float* __restrict__ pred,
                                      const float2* __restrict__ EXY, int i,
                                      float& ex, float& ey) {
  if constexpr (FAT) { float2 e = EXY[i]; ex = e.x; ey = e.y; }
  else compute_emb(pred, i, ex, ey);
}
template <bool FAT>
__device__ __forceinline__ float get_sv(const float* __restrict__ pred,
                                        const float* __restrict__ SV, int i) {
  if constexpr (FAT) return SV[i];
  else return 1.0f / (1.0f + expf(-pred[(size_t)4 * NPIX + i]));
}
template <bool FAT>
__device__ __forceinline__ float get_sm_v(const float* __restrict__ pred,
                                          const float* __restrict__ SM, int i) {
  if constexpr (FAT) return SM[i];
  else return compute_sm(pred, i);
}

// block-level argmax(val, first index) + two int sums. Deterministic.
__device__ __forceinline__ void block_reduce(float& v, int& idx, int& s1, int& s2,
                                             float* lV, int* lI, int* lS, int* lS2) {
  int tid = threadIdx.x;
  lV[tid] = v; lI[tid] = idx; lS[tid] = s1; lS2[tid] = s2;
  __syncthreads();
  for (int off = TPB >> 1; off > 0; off >>= 1) {
    if (tid < off) {
      float vo = lV[tid + off]; int io = lI[tid + off];
      if (vo > lV[tid] || (vo == lV[tid] && io < lI[tid])) { lV[tid] = vo; lI[tid] = io; }
      lS[tid] += lS[tid + off];
      lS2[tid] += lS2[tid + off];
    }
    __syncthreads();
  }
  v = lV[0]; idx = lI[0]; s1 = lS[0]; s2 = lS2[0];
  __syncthreads();
}

// ---- hierarchical grid barrier: returns true in the last-arriving block ----
__device__ __forceinline__ bool bar_enter(int* CTL, int nblk) {
  __shared__ int s_lastf;
  __threadfence();           // agent release: prior stores reach coherence point
  __syncthreads();
  if (threadIdx.x == 0) {
    int g = blockIdx.x & (NGRP - 1);
    int gsz = ((nblk - 1 - g) >> 6) + 1;   // #blocks with blockIdx%64==g
    int r = __hip_atomic_fetch_add(&CTL[g * 32], 1, __ATOMIC_ACQ_REL, __HIP_MEMORY_SCOPE_AGENT);
    int last = 0;
    if (r == gsz - 1) {
      int ng = nblk < NGRP ? nblk : NGRP;
      int r2 = __hip_atomic_fetch_add(&CTL[CTL_ROOT], 1, __ATOMIC_ACQ_REL, __HIP_MEMORY_SCOPE_AGENT);
      last = (r2 == ng - 1);
    }
    s_lastf = last;
  }
  __syncthreads();
  return s_lastf != 0;
}

__device__ __forceinline__ void bar_release(int* CTL) {
  __syncthreads();
  if (threadIdx.x < NGRP) as_(&CTL[threadIdx.x * 32], 0);
  if (threadIdx.x == NGRP) as_(&CTL[CTL_ROOT], 0);
  __threadfence();
  __syncthreads();
  if (threadIdx.x == 0)
    __hip_atomic_fetch_add(&CTL[CTL_GEN], 1, __ATOMIC_RELEASE, __HIP_MEMORY_SCOPE_AGENT);
}

__device__ __forceinline__ void bar_wait(int* CTL, int target) {
  if (threadIdx.x == 0) {
    while (__hip_atomic_load(&CTL[CTL_GEN], __ATOMIC_ACQUIRE, __HIP_MEMORY_SCOPE_AGENT) < target)
      __builtin_amdgcn_s_sleep(16);
  }
  __syncthreads();
}

// last-block finish: argmax+sum reduce over partials, store scalars + seed center
template <bool FAT>
__device__ __forceinline__ void finish_vis(int* CTL, const int* AVI, const int* AI, const int* AS,
                                           int nblk, int base, bool zeroflags,
                                           const float* __restrict__ pred,
                                           const float2* __restrict__ EXY,
                                           float* lV, int* lI, int* lS, int* lS2) {
  float bv = -FLT_MAX; int bi = INT_MAX; int bs = 0, d = 0;
  for (int b = threadIdx.x; b < nblk; b += TPB) {
    float vv = __int_as_float(al(&AVI[b]));
    int ii = al(&AI[b]);
    bs += al(&AS[b]);
    if (vv > bv || (vv == bv && ii < bi)) { bv = vv; bi = ii; }
  }
  block_reduce(bv, bi, bs, d, lV, lI, lS, lS2);
  if (threadIdx.x == 0) {
    int* S = &CTL[CTL_SCAL];
    asf(&S[base + 0], bv); as_(&S[base + 1], bi); as_(&S[base + 2], bs);
    int bj = (bi >= 0 && bi < NPIX) ? bi : 0;   // guard (unused when empty)
    float cx, cy; get_e<FAT>(pred, EXY, bj, cx, cy);
    asf(&S[base + 3], cx); asf(&S[base + 4], cy);
    asf(&S[base + 5], expf(pred[(size_t)2 * NPIX + bj] * 10.0f));
    asf(&S[base + 6], expf(pred[(size_t)3 * NPIX + bj] * 10.0f));
    if (zeroflags) { as_(&S[18], 0); as_(&S[19], 0); }
  }
}

__device__ __forceinline__ void finish_ss(int* CTL, const int* AS, const int* AS2, int nblk,
                                          float* lV, int* lI, int* lS, int* lS2) {
  float fd = -FLT_MAX; int id = INT_MAX; int s1 = 0, s2 = 0;
  for (int b = threadIdx.x; b < nblk; b += TPB) { s1 += al(&AS[b]); s2 += al(&AS2[b]); }
  block_reduce(fd, id, s1, s2, lV, lI, lS, lS2);
  if (threadIdx.x == 0) { as_(&CTL[CTL_SCAL + 16], s1); as_(&CTL[CTL_SCAL + 17], s2); }
}

template <bool FAT>
__global__ void precompute_kernel(const float* __restrict__ pred, int* __restrict__ out,
                                  char* __restrict__ ws) {
  uint64_t* MASKW = (uint64_t*)(ws + OFF_MASK);
  uint64_t* UNCLW = (uint64_t*)(ws + OFF_UNCL);
  int* CTL = (int*)(ws + OFF_CTL);
  float* SMw = (float*)(ws + OFF_SM);
  float* SVw = (float*)(ws + OFF_SV);
  float2* EXYw = (float2*)(ws + OFF_EXY);
  int gid = blockIdx.x * blockDim.x + threadIdx.x;
  int stride = gridDim.x * blockDim.x;   // multiple of 64
  for (int i = gid; i < NPIX; i += stride) {
    float smv = compute_sm(pred, i);
    bool m = smv > 0.5f;
    unsigned long long bal = __ballot(m);
    if ((threadIdx.x & 63) == 0) { MASKW[i >> 6] = bal; UNCLW[i >> 6] = bal; }
    out[i] = 0;
    if constexpr (FAT) {
      SMw[i] = smv;
      SVw[i] = 1.0f / (1.0f + expf(-pred[(size_t)4 * NPIX + i]));
      float ex, ey; compute_emb(pred, i, ex, ey);
      EXYw[i] = make_float2(ex, ey);
    }
  }
  if (gid < 4096) CTL[gid] = 0;
}

template <bool FAT>
__global__ __launch_bounds__(TPB) void cluster_kernel(const float* __restrict__ pred,
                                                      int* __restrict__ out,
                                                      char* __restrict__ ws, int nblk) {
  uint64_t* MASKW = (uint64_t*)(ws + OFF_MASK);
  uint64_t* UNCLW = (uint64_t*)(ws + OFF_UNCL);
  uint64_t* P1W = (uint64_t*)(ws + OFF_P1);
  uint64_t* P2W = (uint64_t*)(ws + OFF_P2);
  int* AVI = (int*)(ws + OFF_AV);
  int* AI = (int*)(ws + OFF_AI);
  int* AS = (int*)(ws + OFF_AS);
  int* AS2 = (int*)(ws + OFF_AS2);
  int* CTL = (int*)(ws + OFF_CTL);
  const float* SM = (const float*)(ws + OFF_SM);
  const float* SV = (const float*)(ws + OFF_SV);
  const float2* EXY = (const float2*)(ws + OFF_EXY);
  int* S = &CTL[CTL_SCAL];

  const int tid = threadIdx.x;
  const int lane = tid & 63;
  const int nw = nblk * (TPB / 64);
  const int gw0 = blockIdx.x * (TPB / 64) + (tid >> 6);

  __shared__ float lV[TPB];
  __shared__ int lI[TPB], lS[TPB], lS2[TPB];
  __shared__ int lbin[256];
  __shared__ int s_sc[24];

  int ph = 0;
  bool last;

  // ---- initial pass A: sum(uncl), argmax(seed_map over uncl) ----
  {
    float bv = -FLT_MAX; int bi = INT_MAX; int s = 0, d = 0;
    for (int w = gw0; w < NWORD; w += nw) {
      uint64_t uw = UNCLW[w];
      if (uw) {
        int i = (w << 6) | lane;
        if ((uw >> lane) & 1ull) {
          s++;
          float v = get_sm_v<FAT>(pred, SM, i);
          if (v > bv || (v == bv && i < bi)) { bv = v; bi = i; }
        }
      }
    }
    block_reduce(bv, bi, s, d, lV, lI, lS, lS2);
    if (tid == 0) { asf(&AVI[blockIdx.x], bv); as_(&AI[blockIdx.x], bi); as_(&AS[blockIdx.x], s); }
  }
  last = bar_enter(CTL, nblk); ++ph;
  if (last) { finish_vis<FAT>(CTL, AVI, AI, AS, nblk, 0, false, pred, EXY, lV, lI, lS, lS2); bar_release(CTL); }
  else bar_wait(CTL, ph);
  if (tid < 24) s_sc[tid] = al(&S[tid]);
  __syncthreads();
  float val1 = __int_as_float(s_sc[0]); int seed1 = s_sc[1]; int Sall = s_sc[2];
  float cx1 = __int_as_float(s_sc[3]), cy1 = __int_as_float(s_sc[4]);
  float sx1 = __int_as_float(s_sc[5]), sy1 = __int_as_float(s_sc[6]);

  int count = 1, it = 0;
  while (Sall > 160 && count < 200 && it < 2000) {
    if (val1 < 0.5f) break;

    // ---- pass B: prop1 bits, cnt1, seed2 = argmax(sigmoid(seed_val) | prop1) ----
    {
      float bv = -FLT_MAX; int bi = INT_MAX; int c1 = 0, d = 0;
      for (int w0 = gw0; w0 < NWORD; w0 += nw * UNROLL) {
        int wa[UNROLL]; uint64_t mwa[UNROLL];
#pragma unroll
        for (int u = 0; u < UNROLL; u++) {
          wa[u] = w0 + u * nw;
          mwa[u] = (wa[u] < NWORD) ? MASKW[wa[u]] : 0ull;
        }
#pragma unroll
        for (int u = 0; u < UNROLL; u++) {
          int w = wa[u];
          if (w >= NWORD) continue;
          uint64_t mw = mwa[u];
          uint64_t r = 0;
          if (mw) {
            int i = (w << 6) | lane;
            float ex, ey; get_e<FAT>(pred, EXY, i, ex, ey);
            bool p = prop_test(ex, ey, cx1, cy1, sx1, sy1) && (((mw >> lane) & 1ull) != 0);
            r = __ballot(p);
            if (p) {
              c1++;
              float v = get_sv<FAT>(pred, SV, i);
              if (v > bv || (v == bv && i < bi)) { bv = v; bi = i; }
            }
          }
          if (lane == 0) P1W[w] = r;
        }
      }
      block_reduce(bv, bi, c1, d, lV, lI, lS, lS2);
      if (tid == 0) { asf(&AVI[blockIdx.x], bv); as_(&AI[blockIdx.x], bi); as_(&AS[blockIdx.x], c1); }
    }
    last = bar_enter(CTL, nblk); ++ph;
    if (last) { finish_vis<FAT>(CTL, AVI, AI, AS, nblk, 8, true, pred, EXY, lV, lI, lS, lS2); bar_release(CTL); }
    else bar_wait(CTL, ph);
    if (tid < 24) s_sc[tid] = al(&S[tid]);
    __syncthreads();
    int seed2 = s_sc[9]; int cnt1 = s_sc[10];
    // NOTE: finish_vis stored at base 8: [8]=svmax,[9]=seed2,[10]=cnt1,[11..14]=center2
    float cx2 = __int_as_float(s_sc[11]), cy2 = __int_as_float(s_sc[12]);
    float sx2 = __int_as_float(s_sc[13]), sy2 = __int_as_float(s_sc[14]);
    bool big1 = cnt1 > 160;

    // ---- pass C: prop2 bits, cnt2, overlap with uncl (+ seed flags) ----
    {
      float fd = -FLT_MAX; int idd = INT_MAX; int c2 = 0, ov = 0;
      for (int w0 = gw0; w0 < NWORD; w0 += nw * UNROLL) {
        int wa[UNROLL]; uint64_t mwa[UNROLL];
#pragma unroll
        for (int u = 0; u < UNROLL; u++) {
          wa[u] = w0 + u * nw;
          mwa[u] = (wa[u] < NWORD) ? MASKW[wa[u]] : 0ull;
        }
#pragma unroll
        for (int u = 0; u < UNROLL; u++) {
          int w = wa[u];
          if (w >= NWORD) continue;
          uint64_t mw = mwa[u];
          uint64_t r = 0;
          if (mw) {
            uint64_t uw = UNCLW[w];
            int i = (w << 6) | lane;
            float ex, ey; get_e<FAT>(pred, EXY, i, ex, ey);
            bool p = prop_test(ex, ey, cx2, cy2, sx2, sy2) && (((mw >> lane) & 1ull) != 0);
            r = __ballot(p);
            bool ub = ((uw >> lane) & 1ull) != 0;
            if (p) { c2++; if (ub) ov++; }
            if (i == seed1) as_(&S[18], p ? 1 : 0);
            if (i == seed2) as_(&S[19], (p && ub) ? 1 : 0);
          }
          if (lane == 0) P2W[w] = r;
        }
      }
      block_reduce(fd, idd, c2, ov, lV, lI, lS, lS2);
      if (tid == 0) { as_(&AS[blockIdx.x], c2); as_(&AS2[blockIdx.x], ov); }
    }
    last = bar_enter(CTL, nblk); ++ph;
    if (last) { finish_ss(CTL, AS, AS2, nblk, lV, lI, lS, lS2); bar_release(CTL); }
    else bar_wait(CTL, ph);
    if (tid < 24) s_sc[tid] = al(&S[tid]);
    __syncthreads();
    int cnt2 = s_sc[16]; int ovl = s_sc[17];
    int f18 = s_sc[18], f19 = s_sc[19];

    // reference clears uncl at seed1 (always; uncl[seed1]==1 by construction)
    // and seed2 (if big1) BEFORE the overlap sum; subtract those from ovl.
    ovl -= f18;
    if (big1 && seed2 != seed1) ovl -= f19;

    bool big2 = cnt2 > 160;
    int den = cnt2 > 1 ? cnt2 : 1;
    float ratio = (float)ovl / (float)den;
    bool accept = big1 && big2 && (ratio > 0.5f);
    if (accept && blockIdx.x == 0 && tid == 0) CTL[CTL_SIZ + count] = cnt2;

    // ---- pass D (state update) fused with next pass A ----
    {
      float bv = -FLT_MAX; int bi = INT_MAX; int sA = 0, d = 0;
      for (int w0 = gw0; w0 < NWORD; w0 += nw * UNROLL) {
        int wa[UNROLL]; uint64_t uwa[UNROLL], p2a[UNROLL];
#pragma unroll
        for (int u = 0; u < UNROLL; u++) {
          wa[u] = w0 + u * nw;
          bool inb = wa[u] < NWORD;
          uwa[u] = inb ? UNCLW[wa[u]] : 0ull;
          p2a[u] = inb ? P2W[wa[u]] : 0ull;
        }
#pragma unroll
        for (int u = 0; u < UNROLL; u++) {
          int w = wa[u];
          if (w >= NWORD) continue;
          uint64_t uw = uwa[u], p2w = p2a[u];
          bool need_out = accept && (p2w != 0ull);
          if (uw == 0ull && !need_out) continue;
          uint64_t p1w = big1 ? 0ull : P1W[w];
          int i = (w << 6) | lane;
          bool ub = ((uw >> lane) & 1ull) != 0;
          bool p2 = ((p2w >> lane) & 1ull) != 0;
          bool fp = big1 ? p2 : (((p1w >> lane) & 1ull) != 0);
          bool nu = ub && !(fp || i == seed1 || (big1 && i == seed2));
          uint64_t r = __ballot(nu);
          if (lane == 0 && uw) UNCLW[w] = r;
          if (accept && p2) out[i] = count;
          if (nu) {
            sA++;
            float v = get_sm_v<FAT>(pred, SM, i);
            if (v > bv || (v == bv && i < bi)) { bv = v; bi = i; }
          }
        }
      }
      block_reduce(bv, bi, sA, d, lV, lI, lS, lS2);
      if (tid == 0) { asf(&AVI[blockIdx.x], bv); as_(&AI[blockIdx.x], bi); as_(&AS[blockIdx.x], sA); }
    }
    if (accept) count++;
    it++;
    last = bar_enter(CTL, nblk); ++ph;
    if (last) { finish_vis<FAT>(CTL, AVI, AI, AS, nblk, 0, false, pred, EXY, lV, lI, lS, lS2); bar_release(CTL); }
    else bar_wait(CTL, ph);
    if (tid < 24) s_sc[tid] = al(&S[tid]);
    __syncthreads();
    val1 = __int_as_float(s_sc[0]); seed1 = s_sc[1]; Sall = s_sc[2];
    cx1 = __int_as_float(s_sc[3]); cy1 = __int_as_float(s_sc[4]);
    sx1 = __int_as_float(s_sc[5]); sy1 = __int_as_float(s_sc[6]);
  }

  // ---- post-filter: bincount(now), remove small/overwritten ids ----
  int* NOW = &CTL[CTL_NOW];
  int* SIZ = &CTL[CTL_SIZ];
  lbin[tid] = 0;
  __syncthreads();
  const int gpx = blockIdx.x * TPB + tid;
  const int pstride = nblk * TPB;
  for (int i = gpx; i < NPIX; i += pstride) atomicAdd(&lbin[out[i]], 1);
  __syncthreads();
  if (lbin[tid] > 0) atomicAdd(&NOW[tid], lbin[tid]);
  last = bar_enter(CTL, nblk); ++ph;
  if (last) bar_release(CTL); else bar_wait(CTL, ph);
  for (int i = gpx; i < NPIX; i += pstride) {
    int id = out[i];
    if (id > 0) {
      int n = NOW[id];
      int sz = SIZ[id];
      bool rm = (n != sz) && ((n < 480) || ((float)n < 0.5f * (float)sz));
      if (rm) out[i] = 0;
    }
  }
}

// finish_vis for pass B stores at SCAL base 8: [8]=val,[9]=idx,[10]=sum,[11..14]=center.
// s_sc parsing above matches this layout.

extern "C" void kernel_launch(void* const* d_in, const int* in_sizes, int n_in,
                              void* d_out, int out_size, void* d_ws, size_t ws_size,
                              hipStream_t stream) {
  const float* pred = (const float*)d_in[0];
  int* out = (int*)d_out;
  char* ws = (char*)d_ws;

  bool fat = ws_size >= FAT_NEED;

  int dev = 0;
  hipGetDevice(&dev);
  int numCU = 0;
  hipDeviceGetAttribute(&numCU, hipDeviceAttributeMultiprocessorCount, dev);
  if (numCU <= 0) numCU = 256;

  if (fat) {
    hipLaunchKernelGGL(precompute_kernel<true>, dim3(4096), dim3(TPB), 0, stream, pred, out, ws);
    int maxPerCU = 0;
    int nblk = MAXBLK;
    if (hipOccupancyMaxActiveBlocksPerMultiprocessor(&maxPerCU, (const void*)cluster_kernel<true>,
                                                     TPB, 0) == hipSuccess && maxPerCU > 0) {
      long long cap = (long long)maxPerCU * numCU;
      if (cap < nblk) nblk = (int)cap;
    }
    if (nblk < 1) nblk = 1;
    void* args[] = {(void*)&pred, (void*)&out, (void*)&ws, (void*)&nblk};
    hipLaunchCooperativeKernel((void*)cluster_kernel<true>, dim3(nblk), dim3(TPB), args, 0, stream);
  } else {
    hipLaunchKernelGGL(precompute_kernel<false>, dim3(4096), dim3(TPB), 0, stream, pred, out, ws);
    int maxPerCU = 0;
    int nblk = MAXBLK;
    if (hipOccupancyMaxActiveBlocksPerMultiprocessor(&maxPerCU, (const void*)cluster_kernel<false>,
                                                     TPB, 0) == hipSuccess && maxPerCU > 0) {
      long long cap = (long long)maxPerCU * numCU;
      if (cap < nblk) nblk = (int)cap;
    }
    if (nblk < 1) nblk = 1;
    void* args[] = {(void*)&pred, (void*)&out, (void*)&ws, (void*)&nblk};
    hipLaunchCooperativeKernel((void*)cluster_kernel<false>, dim3(nblk), dim3(TPB), args, 0, stream);
  }
}

// Round 4
// 1389.109 us; speedup vs baseline: 3.2126x; 2.8045x over previous
//
#include <hip/hip_runtime.h>
#include <cfloat>
#include <climits>
#include <cstdint>

#define HH 1024
#define WW 2048
#define NPIX (HH * WW)
#define NWORD (NPIX / 64)
#define TPB 256
#define MAXBLK 2048
#define NGRP 64
#define UNROLL 4
#define NBLK_TARGET 512

// ---- workspace layout (bytes) ----
#define OFF_MASK ((size_t)0x0)
#define OFF_UNCL ((size_t)0x40000)
#define OFF_P1   ((size_t)0x80000)
#define OFF_P2   ((size_t)0xC0000)
#define OFF_PV   ((size_t)0x100000)   // u64 * MAXBLK: packed (val_bits<<32)|idx
#define OFF_PS   ((size_t)0x104000)   // u64 * MAXBLK: packed s | (s2<<32)
#define OFF_CTL  ((size_t)0x108000)   // 4096 ints
#define OFF_SM   ((size_t)0x200000)   // 8 MB
#define OFF_SV   ((size_t)0xA00000)   // 8 MB
#define OFF_EXY  ((size_t)0x1200000)  // 16 MB
#define FAT_NEED ((size_t)0x2200000)  // 34 MB

// CTL int indices: [g*32] g<64 = group counters, 2048 = root, 2112+ = scalar flags,
// 2304 = SIZES[256], 2560 = NOW[256]
#define CTL_ROOT 2048
#define CTL_SCAL 2112
#define CTL_SIZ  2304
#define CTL_NOW  2560

// ---- agent-scope atomics: bypass non-coherent per-XCD L2, land at coherence
// point. NO fences anywhere -> no buffer_wbl2/inv cache maintenance, read-only
// arrays stay hot in L2.
__device__ __forceinline__ int al(const int* p) {
  return __hip_atomic_load((int*)p, __ATOMIC_RELAXED, __HIP_MEMORY_SCOPE_AGENT);
}
__device__ __forceinline__ void as_(int* p, int v) {
  __hip_atomic_store(p, v, __ATOMIC_RELAXED, __HIP_MEMORY_SCOPE_AGENT);
}
__device__ __forceinline__ uint64_t al64(const uint64_t* p) {
  return __hip_atomic_load((uint64_t*)p, __ATOMIC_RELAXED, __HIP_MEMORY_SCOPE_AGENT);
}
__device__ __forceinline__ void as64(uint64_t* p, uint64_t v) {
  __hip_atomic_store(p, v, __ATOMIC_RELAXED, __HIP_MEMORY_SCOPE_AGENT);
}

// seed_map = softmax(pred[5:7], axis=0)[1], replicated op-for-op (max-subtract)
__device__ __forceinline__ float compute_sm(const float* __restrict__ pred, int i) {
  float a = pred[(size_t)5 * NPIX + i];
  float b = pred[(size_t)6 * NPIX + i];
  float m = fmaxf(a, b);
  float ea = expf(a - m);
  float eb = expf(b - m);
  return eb / (ea + eb);
}

// emb = tanh(pred[:2]) + xym ; xym from linspace: c*(2/2047), r*(1/1023)
__device__ __forceinline__ void compute_emb(const float* __restrict__ pred, int i,
                                            float& ex, float& ey) {
#pragma clang fp contract(off)
  int r = i >> 11;
  int c = i & (WW - 1);
  float xm = (float)c * (2.0f / 2047.0f);
  float ym = (float)r * (1.0f / 1023.0f);
  ex = tanhf(pred[i]) + xm;
  ey = tanhf(pred[(size_t)NPIX + i]) + ym;
}

// dist = exp(-((dx*dx)*sx + (dy*dy)*sy)) > 0.5, exact reference association
__device__ __forceinline__ bool prop_test(float ex, float ey, float cx, float cy,
                                          float sx, float sy) {
#pragma clang fp contract(off)
  float dx = ex - cx;
  float dy = ey - cy;
  float t0 = dx * dx; t0 = t0 * sx;
  float t1 = dy * dy; t1 = t1 * sy;
  float d = expf(-(t0 + t1));
  return d > 0.5f;
}

template <bool FAT>
__device__ __forceinline__ void get_e(const float* __restrict__ pred,
                                      const float2* __restrict__ EXY, int i,
                                      float& ex, float& ey) {
  if constexpr (FAT) { float2 e = EXY[i]; ex = e.x; ey = e.y; }
  else compute_emb(pred, i, ex, ey);
}
template <bool FAT>
__device__ __forceinline__ float get_sv(const float* __restrict__ pred,
                                        const float* __restrict__ SV, int i) {
  if constexpr (FAT) return SV[i];
  else return 1.0f / (1.0f + expf(-pred[(size_t)4 * NPIX + i]));
}
template <bool FAT>
__device__ __forceinline__ float get_sm_v(const float* __restrict__ pred,
                                          const float* __restrict__ SM, int i) {
  if constexpr (FAT) return SM[i];
  else return compute_sm(pred, i);
}

// block-level argmax(val, first index) + two int sums. Deterministic.
__device__ __forceinline__ void block_reduce(float& v, int& idx, int& s1, int& s2,
                                             float* lV, int* lI, int* lS, int* lS2) {
  int tid = threadIdx.x;
  lV[tid] = v; lI[tid] = idx; lS[tid] = s1; lS2[tid] = s2;
  __syncthreads();
  for (int off = TPB >> 1; off > 0; off >>= 1) {
    if (tid < off) {
      float vo = lV[tid + off]; int io = lI[tid + off];
      if (vo > lV[tid] || (vo == lV[tid] && io < lI[tid])) { lV[tid] = vo; lI[tid] = io; }
      lS[tid] += lS[tid + off];
      lS2[tid] += lS2[tid + off];
    }
    __syncthreads();
  }
  v = lV[0]; idx = lI[0]; s1 = lS[0]; s2 = lS2[0];
  __syncthreads();
}

// ---- fence-free monotonic tree barrier. ph is 1-based phase number. ----
// Arrivals: ACQ_REL adds (release own prior agent stores; vmcnt(0) drained at
// the preceding __syncthreads covers other lanes' agent stores). Waiters:
// ACQUIRE poll on the monotone root counter. No resets -> no release phase,
// immune to reset races.
__device__ __forceinline__ void gbar(int* CTL, int nblk, int ph) {
  __syncthreads();
  if (threadIdx.x == 0) {
    asm volatile("s_waitcnt vmcnt(0)" ::: "memory");
    int g = blockIdx.x & (NGRP - 1);
    int gsz = ((nblk - 1 - g) >> 6) + 1;   // #blocks with blockIdx%64==g
    int ng = nblk < NGRP ? nblk : NGRP;
    int r = __hip_atomic_fetch_add(&CTL[g * 32], 1, __ATOMIC_ACQ_REL, __HIP_MEMORY_SCOPE_AGENT);
    if (r == ph * gsz - 1)
      __hip_atomic_fetch_add(&CTL[CTL_ROOT], 1, __ATOMIC_ACQ_REL, __HIP_MEMORY_SCOPE_AGENT);
    while (__hip_atomic_load(&CTL[CTL_ROOT], __ATOMIC_ACQUIRE, __HIP_MEMORY_SCOPE_AGENT) < ph * ng)
      __builtin_amdgcn_s_sleep(2);
  }
  __syncthreads();
}

// redundant (every-block) final reduce over packed partials: deterministic,
// identical result in all blocks (fixed loop order, no atomics).
__device__ __forceinline__ void red_vis(const uint64_t* PV, const uint64_t* PS, int nblk,
                                        float& v, int& idx, int& s,
                                        float* lV, int* lI, int* lS, int* lS2) {
  float bv = -FLT_MAX; int bi = INT_MAX; int bs = 0, d = 0;
  for (int b = threadIdx.x; b < nblk; b += TPB) {
    uint64_t pv = al64(&PV[b]);
    float vv = __int_as_float((int)(pv >> 32));
    int ii = (int)(pv & 0xFFFFFFFFull);
    bs += (int)(al64(&PS[b]) & 0xFFFFFFFFull);
    if (vv > bv || (vv == bv && ii < bi)) { bv = vv; bi = ii; }
  }
  block_reduce(bv, bi, bs, d, lV, lI, lS, lS2);
  v = bv; idx = bi; s = bs;
}

__device__ __forceinline__ void red_ss(const uint64_t* PS, int nblk, int& s1, int& s2,
                                       float* lV, int* lI, int* lS, int* lS2) {
  float fd = -FLT_MAX; int id = INT_MAX; int a = 0, b2 = 0;
  for (int b = threadIdx.x; b < nblk; b += TPB) {
    uint64_t ps = al64(&PS[b]);
    a += (int)(ps & 0xFFFFFFFFull);
    b2 += (int)(ps >> 32);
  }
  block_reduce(fd, id, a, b2, lV, lI, lS, lS2);
  s1 = a; s2 = b2;
}

template <bool FAT>
__global__ void precompute_kernel(const float* __restrict__ pred, int* __restrict__ out,
                                  char* __restrict__ ws) {
  uint64_t* MASKW = (uint64_t*)(ws + OFF_MASK);
  uint64_t* UNCLW = (uint64_t*)(ws + OFF_UNCL);
  int* CTL = (int*)(ws + OFF_CTL);
  float* SMw = (float*)(ws + OFF_SM);
  float* SVw = (float*)(ws + OFF_SV);
  float2* EXYw = (float2*)(ws + OFF_EXY);
  int gid = blockIdx.x * blockDim.x + threadIdx.x;
  int stride = gridDim.x * blockDim.x;   // multiple of 64
  for (int i = gid; i < NPIX; i += stride) {
    float smv = compute_sm(pred, i);
    bool m = smv > 0.5f;
    unsigned long long bal = __ballot(m);
    if ((threadIdx.x & 63) == 0) { MASKW[i >> 6] = bal; UNCLW[i >> 6] = bal; }
    out[i] = 0;
    if constexpr (FAT) {
      SMw[i] = smv;
      SVw[i] = 1.0f / (1.0f + expf(-pred[(size_t)4 * NPIX + i]));
      float ex, ey; compute_emb(pred, i, ex, ey);
      EXYw[i] = make_float2(ex, ey);
    }
  }
  if (gid < 4096) CTL[gid] = 0;
}

template <bool FAT>
__global__ __launch_bounds__(TPB) void cluster_kernel(const float* __restrict__ pred,
                                                      int* __restrict__ out,
                                                      char* __restrict__ ws, int nblk) {
  uint64_t* MASKW = (uint64_t*)(ws + OFF_MASK);
  uint64_t* UNCLW = (uint64_t*)(ws + OFF_UNCL);
  uint64_t* P1W = (uint64_t*)(ws + OFF_P1);
  uint64_t* P2W = (uint64_t*)(ws + OFF_P2);
  uint64_t* PV = (uint64_t*)(ws + OFF_PV);
  uint64_t* PS = (uint64_t*)(ws + OFF_PS);
  int* CTL = (int*)(ws + OFF_CTL);
  const float* SM = (const float*)(ws + OFF_SM);
  const float* SV = (const float*)(ws + OFF_SV);
  const float2* EXY = (const float2*)(ws + OFF_EXY);
  int* S = &CTL[CTL_SCAL];

  const int tid = threadIdx.x;
  const int lane = tid & 63;
  const int nw = nblk * (TPB / 64);
  const int gw0 = blockIdx.x * (TPB / 64) + (tid >> 6);
  const int bid = blockIdx.x;

  __shared__ float lV[TPB];
  __shared__ int lI[TPB], lS[TPB], lS2[TPB];
  __shared__ int lbin[256];

  int ph = 0;

  // ---- initial pass A: sum(uncl), argmax(seed_map over uncl). Plain UNCLW
  // reads are safe here (precompute flushed at kernel boundary; no prior
  // in-kernel writers).
  {
    float bv = -FLT_MAX; int bi = INT_MAX; int s = 0, d = 0;
    for (int w = gw0; w < NWORD; w += nw) {
      uint64_t uw = UNCLW[w];
      if (uw) {
        int i = (w << 6) | lane;
        if ((uw >> lane) & 1ull) {
          s++;
          float v = get_sm_v<FAT>(pred, SM, i);
          if (v > bv || (v == bv && i < bi)) { bv = v; bi = i; }
        }
      }
    }
    block_reduce(bv, bi, s, d, lV, lI, lS, lS2);
    if (tid == 0) {
      as64(&PV[bid], ((uint64_t)(uint32_t)__float_as_int(bv) << 32) | (uint32_t)bi);
      as64(&PS[bid], (uint64_t)(uint32_t)s);
    }
  }
  gbar(CTL, nblk, ++ph);
  float val1; int seed1; int Sall;
  red_vis(PV, PS, nblk, val1, seed1, Sall, lV, lI, lS, lS2);
  float cx1, cy1, sx1, sy1;
  {
    int bj = (seed1 >= 0 && seed1 < NPIX) ? seed1 : 0;
    get_e<FAT>(pred, EXY, bj, cx1, cy1);
    sx1 = expf(pred[(size_t)2 * NPIX + bj] * 10.0f);
    sy1 = expf(pred[(size_t)3 * NPIX + bj] * 10.0f);
  }

  int count = 1, it = 0;
  while (Sall > 160 && count < 200 && it < 2000) {
    if (val1 < 0.5f) break;

    // ---- pass B: prop1 bits, cnt1, seed2 = argmax(sigmoid(seed_val) | prop1) ----
    {
      float bv = -FLT_MAX; int bi = INT_MAX; int c1 = 0, d = 0;
      for (int w0 = gw0; w0 < NWORD; w0 += nw * UNROLL) {
        int wa[UNROLL]; uint64_t mwa[UNROLL];
#pragma unroll
        for (int u = 0; u < UNROLL; u++) {
          wa[u] = w0 + u * nw;
          mwa[u] = (wa[u] < NWORD) ? MASKW[wa[u]] : 0ull;   // read-only, L2-hot
        }
#pragma unroll
        for (int u = 0; u < UNROLL; u++) {
          int w = wa[u];
          if (w >= NWORD) continue;
          uint64_t mw = mwa[u];
          uint64_t r = 0;
          if (mw) {
            int i = (w << 6) | lane;
            float ex, ey; get_e<FAT>(pred, EXY, i, ex, ey);
            bool p = prop_test(ex, ey, cx1, cy1, sx1, sy1) && (((mw >> lane) & 1ull) != 0);
            r = __ballot(p);
            if (p) {
              c1++;
              float v = get_sv<FAT>(pred, SV, i);
              if (v > bv || (v == bv && i < bi)) { bv = v; bi = i; }
            }
          }
          if (lane == 0) as64(&P1W[w], r);
        }
      }
      block_reduce(bv, bi, c1, d, lV, lI, lS, lS2);
      if (tid == 0) {
        as64(&PV[bid], ((uint64_t)(uint32_t)__float_as_int(bv) << 32) | (uint32_t)bi);
        as64(&PS[bid], (uint64_t)(uint32_t)c1);
      }
    }
    gbar(CTL, nblk, ++ph);
    float svmax; int seed2; int cnt1;
    red_vis(PV, PS, nblk, svmax, seed2, cnt1, lV, lI, lS, lS2);
    bool big1 = cnt1 > 160;
    float cx2, cy2, sx2, sy2;
    {
      int bj = (seed2 >= 0 && seed2 < NPIX) ? seed2 : 0;
      get_e<FAT>(pred, EXY, bj, cx2, cy2);
      sx2 = expf(pred[(size_t)2 * NPIX + bj] * 10.0f);
      sy2 = expf(pred[(size_t)3 * NPIX + bj] * 10.0f);
    }

    // ---- pass C: prop2 bits, cnt2, overlap with uncl (+ seed flags) ----
    {
      int c2 = 0, ov = 0;
      float fd = -FLT_MAX; int idd = INT_MAX;
      for (int w0 = gw0; w0 < NWORD; w0 += nw * UNROLL) {
        int wa[UNROLL]; uint64_t mwa[UNROLL], uwa[UNROLL];
#pragma unroll
        for (int u = 0; u < UNROLL; u++) {
          wa[u] = w0 + u * nw;
          bool inb = wa[u] < NWORD;
          mwa[u] = inb ? MASKW[wa[u]] : 0ull;
          uwa[u] = inb ? al64(&UNCLW[wa[u]]) : 0ull;
        }
#pragma unroll
        for (int u = 0; u < UNROLL; u++) {
          int w = wa[u];
          if (w >= NWORD) continue;
          uint64_t mw = mwa[u];
          uint64_t r = 0;
          if (mw) {
            uint64_t uw = uwa[u];
            int i = (w << 6) | lane;
            float ex, ey; get_e<FAT>(pred, EXY, i, ex, ey);
            bool p = prop_test(ex, ey, cx2, cy2, sx2, sy2) && (((mw >> lane) & 1ull) != 0);
            r = __ballot(p);
            bool ub = ((uw >> lane) & 1ull) != 0;
            if (p) { c2++; if (ub) ov++; }
            // flags: written unconditionally by the single owning lane grid-wide
            if (i == seed1) as_(&S[18], p ? 1 : 0);
            if (i == seed2) as_(&S[19], (p && ub) ? 1 : 0);
          }
          if (lane == 0) as64(&P2W[w], r);
        }
      }
      block_reduce(fd, idd, c2, ov, lV, lI, lS, lS2);
      if (tid == 0)
        as64(&PS[bid], (uint64_t)(uint32_t)c2 | ((uint64_t)(uint32_t)ov << 32));
    }
    gbar(CTL, nblk, ++ph);
    int cnt2, ovl;
    red_ss(PS, nblk, cnt2, ovl, lV, lI, lS, lS2);
    int f18 = al(&S[18]);
    int f19 = al(&S[19]);

    // reference clears uncl at seed1 (always; uncl[seed1]==1 by construction)
    // and seed2 (if big1) BEFORE the overlap sum; subtract those from ovl.
    ovl -= f18;
    if (big1 && seed2 != seed1) ovl -= f19;

    bool big2 = cnt2 > 160;
    int den = cnt2 > 1 ? cnt2 : 1;
    float ratio = (float)ovl / (float)den;
    bool accept = big1 && big2 && (ratio > 0.5f);
    if (accept && bid == 0 && tid == 0) as_(&CTL[CTL_SIZ + count], cnt2);

    // ---- pass D (state update) fused with next pass A ----
    {
      float bv = -FLT_MAX; int bi = INT_MAX; int sA = 0, d = 0;
      for (int w0 = gw0; w0 < NWORD; w0 += nw * UNROLL) {
        int wa[UNROLL]; uint64_t uwa[UNROLL], p2a[UNROLL];
#pragma unroll
        for (int u = 0; u < UNROLL; u++) {
          wa[u] = w0 + u * nw;
          bool inb = wa[u] < NWORD;
          uwa[u] = inb ? al64(&UNCLW[wa[u]]) : 0ull;
          p2a[u] = inb ? al64(&P2W[wa[u]]) : 0ull;
        }
#pragma unroll
        for (int u = 0; u < UNROLL; u++) {
          int w = wa[u];
          if (w >= NWORD) continue;
          uint64_t uw = uwa[u], p2w = p2a[u];
          bool need_out = accept && (p2w != 0ull);
          if (uw == 0ull && !need_out) continue;
          uint64_t p1w = big1 ? 0ull : al64(&P1W[w]);
          int i = (w << 6) | lane;
          bool ub = ((uw >> lane) & 1ull) != 0;
          bool p2 = ((p2w >> lane) & 1ull) != 0;
          bool fp = big1 ? p2 : (((p1w >> lane) & 1ull) != 0);
          bool nu = ub && !(fp || i == seed1 || (big1 && i == seed2));
          uint64_t r = __ballot(nu);
          if (lane == 0 && uw) as64(&UNCLW[w], r);
          if (accept && p2) out[i] = count;   // plain: same-wave ownership end-to-end
          if (nu) {
            sA++;
            float v = get_sm_v<FAT>(pred, SM, i);
            if (v > bv || (v == bv && i < bi)) { bv = v; bi = i; }
          }
        }
      }
      block_reduce(bv, bi, sA, d, lV, lI, lS, lS2);
      if (tid == 0) {
        as64(&PV[bid], ((uint64_t)(uint32_t)__float_as_int(bv) << 32) | (uint32_t)bi);
        as64(&PS[bid], (uint64_t)(uint32_t)sA);
      }
    }
    if (accept) count++;
    it++;
    gbar(CTL, nblk, ++ph);
    red_vis(PV, PS, nblk, val1, seed1, Sall, lV, lI, lS, lS2);
    {
      int bj = (seed1 >= 0 && seed1 < NPIX) ? seed1 : 0;
      get_e<FAT>(pred, EXY, bj, cx1, cy1);
      sx1 = expf(pred[(size_t)2 * NPIX + bj] * 10.0f);
      sy1 = expf(pred[(size_t)3 * NPIX + bj] * 10.0f);
    }
  }

  // ---- post-filter: bincount(now), remove small/overwritten ids ----
  int* NOW = &CTL[CTL_NOW];
  int* SIZ = &CTL[CTL_SIZ];
  lbin[tid] = 0;
  __syncthreads();
  const int gpx = blockIdx.x * TPB + tid;
  const int pstride = nblk * TPB;
  for (int i = gpx; i < NPIX; i += pstride) atomicAdd(&lbin[out[i]], 1);
  __syncthreads();
  if (lbin[tid] > 0)
    __hip_atomic_fetch_add(&NOW[tid], lbin[tid], __ATOMIC_RELAXED, __HIP_MEMORY_SCOPE_AGENT);
  gbar(CTL, nblk, ++ph);
  // cache NOW/SIZ into LDS once per block (avoid 2M agent loads)
  lS[tid] = al(&NOW[tid]);
  lS2[tid] = al(&SIZ[tid]);
  __syncthreads();
  for (int i = gpx; i < NPIX; i += pstride) {
    int id = out[i];
    if (id > 0) {
      int n = lS[id];
      int sz = lS2[id];
      bool rm = (n != sz) && ((n < 480) || ((float)n < 0.5f * (float)sz));
      if (rm) out[i] = 0;
    }
  }
}

extern "C" void kernel_launch(void* const* d_in, const int* in_sizes, int n_in,
                              void* d_out, int out_size, void* d_ws, size_t ws_size,
                              hipStream_t stream) {
  const float* pred = (const float*)d_in[0];
  int* out = (int*)d_out;
  char* ws = (char*)d_ws;

  bool fat = ws_size >= FAT_NEED;

  int dev = 0;
  hipGetDevice(&dev);
  int numCU = 0;
  hipDeviceGetAttribute(&numCU, hipDeviceAttributeMultiprocessorCount, dev);
  if (numCU <= 0) numCU = 256;

  if (fat) {
    hipLaunchKernelGGL(precompute_kernel<true>, dim3(4096), dim3(TPB), 0, stream, pred, out, ws);
    int maxPerCU = 0;
    int nblk = NBLK_TARGET;
    if (hipOccupancyMaxActiveBlocksPerMultiprocessor(&maxPerCU, (const void*)cluster_kernel<true>,
                                                     TPB, 0) == hipSuccess && maxPerCU > 0) {
      long long cap = (long long)maxPerCU * numCU;
      if (cap < nblk) nblk = (int)cap;
    }
    if (nblk < 1) nblk = 1;
    void* args[] = {(void*)&pred, (void*)&out, (void*)&ws, (void*)&nblk};
    hipLaunchCooperativeKernel((void*)cluster_kernel<true>, dim3(nblk), dim3(TPB), args, 0, stream);
  } else {
    hipLaunchKernelGGL(precompute_kernel<false>, dim3(4096), dim3(TPB), 0, stream, pred, out, ws);
    int maxPerCU = 0;
    int nblk = NBLK_TARGET;
    if (hipOccupancyMaxActiveBlocksPerMultiprocessor(&maxPerCU, (const void*)cluster_kernel<false>,
                                                     TPB, 0) == hipSuccess && maxPerCU > 0) {
      long long cap = (long long)maxPerCU * numCU;
      if (cap < nblk) nblk = (int)cap;
    }
    if (nblk < 1) nblk = 1;
    void* args[] = {(void*)&pred, (void*)&out, (void*)&ws, (void*)&nblk};
    hipLaunchCooperativeKernel((void*)cluster_kernel<false>, dim3(nblk), dim3(TPB), args, 0, stream);
  }
}

// Round 5
// 568.609 us; speedup vs baseline: 7.8485x; 2.4430x over previous
//
#include <hip/hip_runtime.h>
#include <cfloat>
#include <climits>
#include <cstdint>

#define HH 1024
#define WW 2048
#define NPIX (HH * WW)
#define NWORD (NPIX / 64)
#define TPB 256
#define NBLK_MAX 256
#define UNROLL 4
#define MAXI 200

// ---- workspace layout (bytes) ----
#define OFF_MASK ((size_t)0x0)        // 256 KB mask bitwords (read-only after precompute)
#define OFF_UNCL ((size_t)0x40000)    // 256 KB uncl bitwords (wave-private -> plain)
#define OFF_P1   ((size_t)0x80000)    // 256 KB prop1 bitwords (wave-private -> plain)
#define OFF_PV   ((size_t)0xC0000)    // 2 x 256 u64 argmax partials (parity dbuf)
#define OFF_PSA  ((size_t)0xC2000)    // 2 x 256 u64 sum partials
#define OFF_PSB  ((size_t)0xC4000)    // 2 x 256 u64 sum partials
#define OFF_CTL  ((size_t)0xD0000)    // 16384 ints: slots/REL/flags/NOW
#define OFF_SM   ((size_t)0x200000)   // 8 MB seed_map
#define OFF_SV   ((size_t)0xA00000)   // 8 MB sigmoid(seed_val)
#define OFF_EXY  ((size_t)0x1200000)  // 16 MB embeddings
#define FAT_NEED ((size_t)0x2200000)

// CTL int indices: slot for block b at b*32 (128B apart, b<256)
#define CTL_REL  8192
#define CTL_FLG1 8224
#define CTL_FLG2 8225
#define CTL_NOW  8256   // 256 ints
#define CTL_ZEND 16384

// ---- relaxed agent-scope atomics: bypass non-coherent per-XCD L2, complete at
// the coherence point (L3). No acquire/release -> no cache-maintenance ops;
// cross-block ordering comes from the vmcnt(0) drain __syncthreads emits plus
// the slot/REL observation chain in gbar.
__device__ __forceinline__ int al(const int* p) {
  return __hip_atomic_load((int*)p, __ATOMIC_RELAXED, __HIP_MEMORY_SCOPE_AGENT);
}
__device__ __forceinline__ void as_(int* p, int v) {
  __hip_atomic_store(p, v, __ATOMIC_RELAXED, __HIP_MEMORY_SCOPE_AGENT);
}
__device__ __forceinline__ uint64_t al64(const uint64_t* p) {
  return __hip_atomic_load((uint64_t*)p, __ATOMIC_RELAXED, __HIP_MEMORY_SCOPE_AGENT);
}
__device__ __forceinline__ void as64(uint64_t* p, uint64_t v) {
  __hip_atomic_store(p, v, __ATOMIC_RELAXED, __HIP_MEMORY_SCOPE_AGENT);
}

// seed_map = softmax(pred[5:7], axis=0)[1], op-for-op (max-subtract)
__device__ __forceinline__ float compute_sm(const float* __restrict__ pred, int i) {
  float a = pred[(size_t)5 * NPIX + i];
  float b = pred[(size_t)6 * NPIX + i];
  float m = fmaxf(a, b);
  float ea = expf(a - m);
  float eb = expf(b - m);
  return eb / (ea + eb);
}

__device__ __forceinline__ void compute_emb(const float* __restrict__ pred, int i,
                                            float& ex, float& ey) {
#pragma clang fp contract(off)
  int r = i >> 11;
  int c = i & (WW - 1);
  float xm = (float)c * (2.0f / 2047.0f);
  float ym = (float)r * (1.0f / 1023.0f);
  ex = tanhf(pred[i]) + xm;
  ey = tanhf(pred[(size_t)NPIX + i]) + ym;
}

__device__ __forceinline__ bool prop_test(float ex, float ey, float cx, float cy,
                                          float sx, float sy) {
#pragma clang fp contract(off)
  float dx = ex - cx;
  float dy = ey - cy;
  float t0 = dx * dx; t0 = t0 * sx;
  float t1 = dy * dy; t1 = t1 * sy;
  float d = expf(-(t0 + t1));
  return d > 0.5f;
}

template <bool FAT>
__device__ __forceinline__ void get_e(const float* __restrict__ pred,
                                      const float2* __restrict__ EXY, int i,
                                      float& ex, float& ey) {
  if constexpr (FAT) { float2 e = EXY[i]; ex = e.x; ey = e.y; }
  else compute_emb(pred, i, ex, ey);
}
template <bool FAT>
__device__ __forceinline__ float get_sv(const float* __restrict__ pred,
                                        const float* __restrict__ SV, int i) {
  if constexpr (FAT) return SV[i];
  else return 1.0f / (1.0f + expf(-pred[(size_t)4 * NPIX + i]));
}
template <bool FAT>
__device__ __forceinline__ float get_sm_v(const float* __restrict__ pred,
                                          const float* __restrict__ SM, int i) {
  if constexpr (FAT) return SM[i];
  else return compute_sm(pred, i);
}

// center params for a seed; guard idx<0 -> pixel 0 (matches jnp.argmax of all-zero = 0)
template <bool FAT>
__device__ __forceinline__ void fetch_cen(const float* __restrict__ pred,
                                          const float2* __restrict__ EXY, int seed,
                                          float& cx, float& cy, float& sx, float& sy) {
  int bj = (seed >= 0 && seed < NPIX) ? seed : 0;
  get_e<FAT>(pred, EXY, bj, cx, cy);
  sx = expf(pred[(size_t)2 * NPIX + bj] * 10.0f);
  sy = expf(pred[(size_t)3 * NPIX + bj] * 10.0f);
}

__device__ __forceinline__ uint64_t sh64(uint64_t v, int m) {
  return (uint64_t)__shfl_xor((unsigned long long)v, m, 64);
}

// block reduce: key = max (packed (val_bits<<32)|~idx : max val, then min idx),
// sa/sb = u64 sums (may carry two u32 fields; totals < 2^22 so no cross-carry).
// Deterministic: fixed combine order.
__device__ __forceinline__ void bred(uint64_t& key, uint64_t& sa, uint64_t& sb,
                                     uint64_t* lK, uint64_t* lA, uint64_t* lB) {
#pragma unroll
  for (int m = 1; m < 64; m <<= 1) {
    uint64_t k2 = sh64(key, m); if (k2 > key) key = k2;
    sa += sh64(sa, m);
    sb += sh64(sb, m);
  }
  int wid = threadIdx.x >> 6;
  if ((threadIdx.x & 63) == 0) { lK[wid] = key; lA[wid] = sa; lB[wid] = sb; }
  __syncthreads();
  key = lK[0]; sa = lA[0]; sb = lB[0];
#pragma unroll
  for (int w = 1; w < TPB / 64; w++) {
    uint64_t k2 = lK[w]; if (k2 > key) key = k2;
    sa += lA[w]; sb += lB[w];
  }
  __syncthreads();
}

// redundant global reduce over per-block partials (every block, identical order)
__device__ __forceinline__ void gred(const uint64_t* PVp, const uint64_t* PAp,
                                     const uint64_t* PBp, int nblk,
                                     uint64_t& key, uint64_t& sa, uint64_t& sb,
                                     uint64_t* lK, uint64_t* lA, uint64_t* lB) {
  int t = threadIdx.x;
  key = (t < nblk) ? al64(&PVp[t]) : 0ull;
  sa = (t < nblk) ? al64(&PAp[t]) : 0ull;
  sb = (t < nblk) ? al64(&PBp[t]) : 0ull;
  bred(key, sa, sb, lK, lA, lB);
}

// ---- contention-free slot barrier. Monotone phase values, no resets, no RMW.
// Arrival: own-slot store (after the vmcnt(0) drain of __syncthreads).
// Block 0 wave 0 sweeps slots, publishes monotone REL; others poll REL.
__device__ __forceinline__ void gbar(int* CTL, int nblk, int ph) {
  __syncthreads();   // compiler emits s_waitcnt vmcnt(0) before s_barrier
  if (threadIdx.x == 0) {
    asm volatile("s_waitcnt vmcnt(0)" ::: "memory");
    as_(&CTL[blockIdx.x * 32], ph);
  }
  if (blockIdx.x == 0) {
    if (threadIdx.x < 64) {
      for (;;) {
        bool ok = true;
        for (int b = (int)threadIdx.x; b < nblk; b += 64)
          ok &= (al(&CTL[b * 32]) >= ph);
        if (__all(ok)) break;
        __builtin_amdgcn_s_sleep(1);
      }
      asm volatile("" ::: "memory");
      if (threadIdx.x == 0) as_(&CTL[CTL_REL], ph);
    }
  } else {
    if (threadIdx.x == 0) {
      while (al(&CTL[CTL_REL]) < ph) __builtin_amdgcn_s_sleep(1);
      asm volatile("" ::: "memory");
    }
  }
  __syncthreads();
}

template <bool FAT>
__global__ void precompute_kernel(const float* __restrict__ pred, int* __restrict__ out,
                                  char* __restrict__ ws) {
  uint64_t* MASKW = (uint64_t*)(ws + OFF_MASK);
  uint64_t* UNCLW = (uint64_t*)(ws + OFF_UNCL);
  int* CTL = (int*)(ws + OFF_CTL);
  float* SMw = (float*)(ws + OFF_SM);
  float* SVw = (float*)(ws + OFF_SV);
  float2* EXYw = (float2*)(ws + OFF_EXY);
  int gid = blockIdx.x * blockDim.x + threadIdx.x;
  int stride = gridDim.x * blockDim.x;   // multiple of 64
  for (int i = gid; i < NPIX; i += stride) {
    float smv = compute_sm(pred, i);
    bool m = smv > 0.5f;
    unsigned long long bal = __ballot(m);
    if ((threadIdx.x & 63) == 0) { MASKW[i >> 6] = bal; UNCLW[i >> 6] = bal; }
    out[i] = 0;
    if constexpr (FAT) {
      SMw[i] = smv;
      SVw[i] = 1.0f / (1.0f + expf(-pred[(size_t)4 * NPIX + i]));
      float ex, ey; compute_emb(pred, i, ex, ey);
      EXYw[i] = make_float2(ex, ey);
    }
  }
  if (gid < CTL_ZEND) CTL[gid] = 0;
}

template <bool FAT>
__global__ __launch_bounds__(TPB) void cluster_kernel(const float* __restrict__ pred,
                                                      int* __restrict__ out,
                                                      char* __restrict__ ws, int nblk) {
  uint64_t* MASKW = (uint64_t*)(ws + OFF_MASK);
  uint64_t* UNCLW = (uint64_t*)(ws + OFF_UNCL);
  uint64_t* P1W = (uint64_t*)(ws + OFF_P1);
  uint64_t* PV = (uint64_t*)(ws + OFF_PV);
  uint64_t* PSA = (uint64_t*)(ws + OFF_PSA);
  uint64_t* PSB = (uint64_t*)(ws + OFF_PSB);
  int* CTL = (int*)(ws + OFF_CTL);
  const float* SM = (const float*)(ws + OFF_SM);
  const float* SV = (const float*)(ws + OFF_SV);
  const float2* EXY = (const float2*)(ws + OFF_EXY);

  const int tid = threadIdx.x;
  const int lane = tid & 63;
  const int bid = blockIdx.x;
  const int nw = nblk * (TPB / 64);
  const int gw0 = bid * (TPB / 64) + (tid >> 6);

  __shared__ uint64_t lK[TPB / 64], lA[TPB / 64], lB[TPB / 64];
  __shared__ int lbin[256];
  __shared__ float s_cx[MAXI], s_cy[MAXI], s_sx[MAXI], s_sy[MAXI];
  __shared__ int s_sz[MAXI];

  int ph = 0;

  // ---- pass A0: sum(uncl), argmax(seed_map over uncl) ----
  {
    int par = (ph + 1) & 1;
    uint64_t key = 0, sa = 0, sb = 0;
    for (int w = gw0; w < NWORD; w += nw) {
      uint64_t uw = UNCLW[w];
      if (!uw) continue;
      int i = (w << 6) | lane;
      if ((uw >> lane) & 1ull) {
        sa++;
        float v = get_sm_v<FAT>(pred, SM, i);
        uint64_t k2 = ((uint64_t)(uint32_t)__float_as_int(v) << 32) | (uint32_t)~(uint32_t)i;
        if (k2 > key) key = k2;
      }
    }
    bred(key, sa, sb, lK, lA, lB);
    if (tid == 0) {
      as64(&PV[par * NBLK_MAX + bid], key);
      as64(&PSA[par * NBLK_MAX + bid], sa);
      as64(&PSB[par * NBLK_MAX + bid], sb);
    }
  }
  gbar(CTL, nblk, ++ph);
  float val1; int seed1; int Sall;
  {
    int par = ph & 1;
    uint64_t key, sa, sb;
    gred(PV + par * NBLK_MAX, PSA + par * NBLK_MAX, PSB + par * NBLK_MAX, nblk,
         key, sa, sb, lK, lA, lB);
    val1 = __int_as_float((int)(key >> 32));
    seed1 = (int)~(uint32_t)key;
    Sall = (int)sa;
  }
  float cx1, cy1, sx1, sy1;
  fetch_cen<FAT>(pred, EXY, seed1, cx1, cy1, sx1, sy1);

  int count = 1, it = 0;
  while (Sall > 160 && count < 200 && it < 2000) {
    if (val1 < 0.5f) break;   // 'stop': freeze state, no updates this iteration

    // ---- pass B: prop1 bits, cnt1, seed2 = argmax(sigmoid(seed_val) | prop1) ----
    {
      int par = (ph + 1) & 1;
      uint64_t key = 0, sa = 0, sb = 0;
      for (int w0 = gw0; w0 < NWORD; w0 += nw * UNROLL) {
#pragma unroll
        for (int u = 0; u < UNROLL; u++) {
          int w = w0 + u * nw;
          if (w >= NWORD) continue;
          uint64_t mw = MASKW[w];
          if (!mw) continue;     // stale P1W harmless: uncl==0 there
          int i = (w << 6) | lane;
          bool p = false;
          if ((mw >> lane) & 1ull) {
            float ex, ey; get_e<FAT>(pred, EXY, i, ex, ey);
            p = prop_test(ex, ey, cx1, cy1, sx1, sy1);
          }
          uint64_t r = __ballot(p);
          if (lane == 0) P1W[w] = r;   // plain: wave-private
          if (p) {
            sa++;
            float v = get_sv<FAT>(pred, SV, i);
            uint64_t k2 = ((uint64_t)(uint32_t)__float_as_int(v) << 32) | (uint32_t)~(uint32_t)i;
            if (k2 > key) key = k2;
          }
        }
      }
      bred(key, sa, sb, lK, lA, lB);
      if (tid == 0) {
        as64(&PV[par * NBLK_MAX + bid], key);
        as64(&PSA[par * NBLK_MAX + bid], sa);
        as64(&PSB[par * NBLK_MAX + bid], sb);
      }
    }
    gbar(CTL, nblk, ++ph);
    int seed2, cnt1;
    {
      int par = ph & 1;
      uint64_t key, sa, sb;
      gred(PV + par * NBLK_MAX, PSA + par * NBLK_MAX, PSB + par * NBLK_MAX, nblk,
           key, sa, sb, lK, lA, lB);
      seed2 = (int)~(uint32_t)key;
      cnt1 = (int)sa;
    }
    bool big1 = cnt1 > 160;
    float cx2, cy2, sx2, sy2;
    fetch_cen<FAT>(pred, EXY, seed2, cx2, cy2, sx2, sy2);

    // ---- pass C (fused update): prop2 cnt/overlap + flags + uncl update +
    //      next-iteration sum/argmax. Nothing here depends on 'accept'. ----
    {
      int par = (ph + 1) & 1;
      uint64_t key = 0, sa = 0, sb = 0;
      for (int w0 = gw0; w0 < NWORD; w0 += nw * UNROLL) {
#pragma unroll
        for (int u = 0; u < UNROLL; u++) {
          int w = w0 + u * nw;
          if (w >= NWORD) continue;
          uint64_t mw = MASKW[w];
          if (!mw) continue;     // uncl==0 there: no update, no counts
          uint64_t uw = UNCLW[w];          // plain: wave-private
          uint64_t p1w = big1 ? 0ull : P1W[w];
          int i = (w << 6) | lane;
          bool p = false;
          if ((mw >> lane) & 1ull) {
            float ex, ey; get_e<FAT>(pred, EXY, i, ex, ey);
            p = prop_test(ex, ey, cx2, cy2, sx2, sy2);
          }
          bool ub = ((uw >> lane) & 1ull) != 0;
          if (p) sa += ub ? 0x100000001ull : 1ull;   // c2 | ov<<32
          // seed-clear corrections for the overlap sum (reference clears uncl
          // at seed1/seed2 before summing uncl2*prop2)
          if (i == seed1) as_(&CTL[CTL_FLG1], p ? 1 : 0);
          if (i == seed2) as_(&CTL[CTL_FLG2], (p && ub) ? 1 : 0);
          bool fp = big1 ? p : (((p1w >> lane) & 1ull) != 0);
          bool nu = ub && !(fp || i == seed1 || (big1 && i == seed2));
          uint64_t r = __ballot(nu);
          if (lane == 0 && uw) UNCLW[w] = r;   // plain: wave-private
          if (nu) {
            sb++;
            float v = get_sm_v<FAT>(pred, SM, i);
            uint64_t k2 = ((uint64_t)(uint32_t)__float_as_int(v) << 32) | (uint32_t)~(uint32_t)i;
            if (k2 > key) key = k2;
          }
        }
      }
      bred(key, sa, sb, lK, lA, lB);
      if (tid == 0) {
        as64(&PV[par * NBLK_MAX + bid], key);
        as64(&PSA[par * NBLK_MAX + bid], sa);
        as64(&PSB[par * NBLK_MAX + bid], sb);
      }
    }
    gbar(CTL, nblk, ++ph);
    {
      int par = ph & 1;
      uint64_t key, sa, sb;
      gred(PV + par * NBLK_MAX, PSA + par * NBLK_MAX, PSB + par * NBLK_MAX, nblk,
           key, sa, sb, lK, lA, lB);
      int cnt2 = (int)(uint32_t)sa;
      int ovl = (int)(uint32_t)(sa >> 32);
      int f18 = al(&CTL[CTL_FLG1]);
      int f19 = al(&CTL[CTL_FLG2]);
      ovl -= f18;
      if (big1 && seed2 != seed1) ovl -= f19;
      bool big2 = cnt2 > 160;
      int den = cnt2 > 1 ? cnt2 : 1;
      float ratio = (float)ovl / (float)den;
      bool accept = big1 && big2 && (ratio > 0.5f);
      if (accept) {
        if (tid == 0) {
          s_cx[count] = cx2; s_cy[count] = cy2;
          s_sx[count] = sx2; s_sy[count] = sy2;
          s_sz[count] = cnt2;
        }
        count++;   // all blocks/threads identically
      }
      it++;
      val1 = __int_as_float((int)(key >> 32));
      seed1 = (int)~(uint32_t)key;
      Sall = (int)sb;
    }
    fetch_cen<FAT>(pred, EXY, seed1, cx1, cy1, sx1, sy1);
  }

  // ---- reconstruction: out[i] = last accepted instance containing i; bincount ----
  lbin[tid] = 0;
  __syncthreads();   // also publishes tid0's s_* log writes block-wide
  for (int w = gw0; w < NWORD; w += nw) {
    uint64_t mw = MASKW[w];
    int i = (w << 6) | lane;
    int id = 0;
    if ((mw >> lane) & 1ull) {
      float ex, ey; get_e<FAT>(pred, EXY, i, ex, ey);
      for (int k = 1; k < count; k++) {
        if (prop_test(ex, ey, s_cx[k], s_cy[k], s_sx[k], s_sy[k])) id = k;
      }
    }
    out[i] = id;                 // plain: read back by same wave below
    atomicAdd(&lbin[id], 1);
  }
  __syncthreads();
  if (lbin[tid] > 0)
    __hip_atomic_fetch_add(&CTL[CTL_NOW + tid], lbin[tid], __ATOMIC_RELAXED,
                           __HIP_MEMORY_SCOPE_AGENT);
  gbar(CTL, nblk, ++ph);
  lbin[tid] = al(&CTL[CTL_NOW + tid]);
  __syncthreads();
  for (int w = gw0; w < NWORD; w += nw) {
    int i = (w << 6) | lane;
    int id = out[i];
    if (id > 0) {
      int n = lbin[id];
      int sz = s_sz[id];
      bool rm = (n != sz) && ((n < 480) || ((float)n < 0.5f * (float)sz));
      if (rm) out[i] = 0;
    }
  }
}

extern "C" void kernel_launch(void* const* d_in, const int* in_sizes, int n_in,
                              void* d_out, int out_size, void* d_ws, size_t ws_size,
                              hipStream_t stream) {
  const float* pred = (const float*)d_in[0];
  int* out = (int*)d_out;
  char* ws = (char*)d_ws;

  bool fat = ws_size >= FAT_NEED;

  int dev = 0;
  hipGetDevice(&dev);
  int numCU = 0;
  hipDeviceGetAttribute(&numCU, hipDeviceAttributeMultiprocessorCount, dev);
  if (numCU <= 0) numCU = 256;

  if (fat) {
    hipLaunchKernelGGL(precompute_kernel<true>, dim3(4096), dim3(TPB), 0, stream, pred, out, ws);
    int maxPerCU = 0;
    int nblk = NBLK_MAX;
    if (hipOccupancyMaxActiveBlocksPerMultiprocessor(&maxPerCU, (const void*)cluster_kernel<true>,
                                                     TPB, 0) == hipSuccess && maxPerCU > 0) {
      long long cap = (long long)maxPerCU * numCU;
      if (cap < nblk) nblk = (int)cap;
    }
    if (nblk < 1) nblk = 1;
    void* args[] = {(void*)&pred, (void*)&out, (void*)&ws, (void*)&nblk};
    hipLaunchCooperativeKernel((void*)cluster_kernel<true>, dim3(nblk), dim3(TPB), args, 0, stream);
  } else {
    hipLaunchKernelGGL(precompute_kernel<false>, dim3(4096), dim3(TPB), 0, stream, pred, out, ws);
    int maxPerCU = 0;
    int nblk = NBLK_MAX;
    if (hipOccupancyMaxActiveBlocksPerMultiprocessor(&maxPerCU, (const void*)cluster_kernel<false>,
                                                     TPB, 0) == hipSuccess && maxPerCU > 0) {
      long long cap = (long long)maxPerCU * numCU;
      if (cap < nblk) nblk = (int)cap;
    }
    if (nblk < 1) nblk = 1;
    void* args[] = {(void*)&pred, (void*)&out, (void*)&ws, (void*)&nblk};
    hipLaunchCooperativeKernel((void*)cluster_kernel<false>, dim3(nblk), dim3(TPB), args, 0, stream);
  }
}

// Round 6
// 301.002 us; speedup vs baseline: 14.8262x; 1.8891x over previous
//
#include <hip/hip_runtime.h>
#include <cfloat>
#include <climits>
#include <cstdint>

#define HH 1024
#define WW 2048
#define NPIX (HH * WW)
#define NWORD (NPIX / 64)
#define TPB 256
#define UNROLL 4
#define MAXI 200

// ================= FAT (compacted) workspace layout =================
#define NBLK_FAT 512
#define F_CTL   ((size_t)0x0)        // ints: slots b*32 (b<512); FLG/CNT/NOW at 16384+
#define F_PV    ((size_t)0x20000)    // 2*512 u64 argmax partials (parity dbuf)
#define F_PSA   ((size_t)0x22000)    // 2*512 u64 sum partials
#define F_PSB   ((size_t)0x24000)
#define F_MASK  ((size_t)0x40000)    // 256 KB mask bitwords
#define F_PCNT  ((size_t)0x80000)    // 128 KB u32 per-word popcount
#define F_WOFF  ((size_t)0xA0000)    // 128 KB u32 per-word exclusive offsets
#define F_UNCL  ((size_t)0xC0000)    // 256 KB compacted uncl bitwords (wave-private)
#define F_P1    ((size_t)0x100000)   // 256 KB compacted prop1 bitwords (wave-private)
#define CMAX    1220000              // entry cap (58% density; actual ~50.1%)
#define F_CIDX  ((size_t)0x140000)
#define F_CEXY  (F_CIDX + (size_t)CMAX * 4 + 512)
#define F_CSM   (F_CEXY + (size_t)CMAX * 8 + 512)
#define F_CSV   (F_CSM + (size_t)CMAX * 4 + 512)
#define F_CSX   (F_CSV + (size_t)CMAX * 4 + 512)
#define F_CSY   (F_CSX + (size_t)CMAX * 4 + 512)
#define FAT_NEED ((size_t)0x2200000)
// F_CTL int indices
#define FC_FLG1 16384
#define FC_FLG2 16385
#define FC_CNT  16386
#define FC_NOW  16400   // 256 ints
#define FC_ZEND 16656

// ================= THIN (round-5 fallback) layout =================
#define T_MASK ((size_t)0x0)
#define T_UNCL ((size_t)0x40000)
#define T_P1   ((size_t)0x80000)
#define T_PV   ((size_t)0xC0000)
#define T_PSA  ((size_t)0xC2000)
#define T_PSB  ((size_t)0xC4000)
#define T_CTL  ((size_t)0xD0000)
#define T_NBLK 256
#define TC_REL  8192
#define TC_FLG1 8224
#define TC_FLG2 8225
#define TC_NOW  8256
#define TC_ZEND 16384

// ---- relaxed agent-scope atomics: bypass non-coherent per-XCD L2, complete at
// the coherence point. No acq/rel fences -> no cache maintenance; read-only data
// stays hot in L2. Ordering via vmcnt(0) drains + slot observation chains.
__device__ __forceinline__ int al(const int* p) {
  return __hip_atomic_load((int*)p, __ATOMIC_RELAXED, __HIP_MEMORY_SCOPE_AGENT);
}
__device__ __forceinline__ void as_(int* p, int v) {
  __hip_atomic_store(p, v, __ATOMIC_RELAXED, __HIP_MEMORY_SCOPE_AGENT);
}
__device__ __forceinline__ uint64_t al64(const uint64_t* p) {
  return __hip_atomic_load((uint64_t*)p, __ATOMIC_RELAXED, __HIP_MEMORY_SCOPE_AGENT);
}
__device__ __forceinline__ void as64(uint64_t* p, uint64_t v) {
  __hip_atomic_store(p, v, __ATOMIC_RELAXED, __HIP_MEMORY_SCOPE_AGENT);
}

// seed_map = softmax(pred[5:7], axis=0)[1], op-for-op (max-subtract)
__device__ __forceinline__ float compute_sm(const float* __restrict__ pred, int i) {
  float a = pred[(size_t)5 * NPIX + i];
  float b = pred[(size_t)6 * NPIX + i];
  float m = fmaxf(a, b);
  float ea = expf(a - m);
  float eb = expf(b - m);
  return eb / (ea + eb);
}

__device__ __forceinline__ void compute_emb(const float* __restrict__ pred, int i,
                                            float& ex, float& ey) {
#pragma clang fp contract(off)
  int r = i >> 11;
  int c = i & (WW - 1);
  float xm = (float)c * (2.0f / 2047.0f);
  float ym = (float)r * (1.0f / 1023.0f);
  ex = tanhf(pred[i]) + xm;
  ey = tanhf(pred[(size_t)NPIX + i]) + ym;
}

__device__ __forceinline__ bool prop_test(float ex, float ey, float cx, float cy,
                                          float sx, float sy) {
#pragma clang fp contract(off)
  float dx = ex - cx;
  float dy = ey - cy;
  float t0 = dx * dx; t0 = t0 * sx;
  float t1 = dy * dy; t1 = t1 * sy;
  float d = expf(-(t0 + t1));
  return d > 0.5f;
}

__device__ __forceinline__ uint64_t sh64(uint64_t v, int m) {
  return (uint64_t)__shfl_xor((unsigned long long)v, m, 64);
}

// block reduce: key = max (packed (val_bits<<32)|~idx), sa/sb u64 sums.
__device__ __forceinline__ void bred(uint64_t& key, uint64_t& sa, uint64_t& sb,
                                     uint64_t* lK, uint64_t* lA, uint64_t* lB) {
#pragma unroll
  for (int m = 1; m < 64; m <<= 1) {
    uint64_t k2 = sh64(key, m); if (k2 > key) key = k2;
    sa += sh64(sa, m);
    sb += sh64(sb, m);
  }
  int wid = threadIdx.x >> 6;
  if ((threadIdx.x & 63) == 0) { lK[wid] = key; lA[wid] = sa; lB[wid] = sb; }
  __syncthreads();
  key = lK[0]; sa = lA[0]; sb = lB[0];
#pragma unroll
  for (int w = 1; w < TPB / 64; w++) {
    uint64_t k2 = lK[w]; if (k2 > key) key = k2;
    sa += lA[w]; sb += lB[w];
  }
  __syncthreads();
}

// redundant global reduce over per-block partials (every block, identical order)
__device__ __forceinline__ void gred(const uint64_t* PVp, const uint64_t* PAp,
                                     const uint64_t* PBp, int nblk,
                                     uint64_t& key, uint64_t& sa, uint64_t& sb,
                                     uint64_t* lK, uint64_t* lA, uint64_t* lB) {
  key = 0; sa = 0; sb = 0;
  for (int b = threadIdx.x; b < nblk; b += TPB) {
    uint64_t k2 = al64(&PVp[b]); if (k2 > key) key = k2;
    sa += al64(&PAp[b]);
    sb += al64(&PBp[b]);
  }
  bred(key, sa, sb, lK, lA, lB);
}

// ---- decentralized slot barrier: arrive (own slot), every block's wave 0
// polls all slots. Monotone phases, no resets, no RMW, no central REL hop.
__device__ __forceinline__ void gbar_d(int* CTL, int nblk, int ph) {
  __syncthreads();   // drains vmcnt -> prior stores are L3-visible before slot store
  if (threadIdx.x == 0) {
    asm volatile("s_waitcnt vmcnt(0)" ::: "memory");
    as_(&CTL[blockIdx.x * 32], ph);
  }
  if (threadIdx.x < 64) {
    for (;;) {
      bool ok = true;
      for (int b = (int)threadIdx.x; b < nblk; b += 64)
        ok &= (al(&CTL[b * 32]) >= ph);
      if (__all(ok)) break;
      __builtin_amdgcn_s_sleep(1);
    }
    asm volatile("" ::: "memory");
  }
  __syncthreads();
}

// ======================= FAT path: precompute =======================
__global__ void pre1_fat(const float* __restrict__ pred, int* __restrict__ out,
                         char* __restrict__ ws) {
  uint64_t* MASKW = (uint64_t*)(ws + F_MASK);
  uint32_t* PCNT = (uint32_t*)(ws + F_PCNT);
  int* CTL = (int*)(ws + F_CTL);
  int gid = blockIdx.x * blockDim.x + threadIdx.x;
  int stride = gridDim.x * blockDim.x;
  int lane = threadIdx.x & 63;
  for (int i = gid; i < NPIX; i += stride) {
    float smv = compute_sm(pred, i);
    unsigned long long bal = __ballot(smv > 0.5f);
    if (lane == 0) { MASKW[i >> 6] = bal; PCNT[i >> 6] = (uint32_t)__popcll(bal); }
    out[i] = 0;
  }
  if (gid < FC_ZEND) CTL[gid] = 0;
}

__global__ void pre2_fat(char* __restrict__ ws) {
  uint32_t* PCNT = (uint32_t*)(ws + F_PCNT);
  uint32_t* WOFF = (uint32_t*)(ws + F_WOFF);
  uint64_t* UNCLC = (uint64_t*)(ws + F_UNCL);
  int* CTL = (int*)(ws + F_CTL);
  __shared__ uint32_t ts[TPB];
  __shared__ int s_cnt;
  int t = threadIdx.x;
  const int W = NWORD / TPB;   // 128 words per thread
  uint32_t sum = 0;
  for (int k = 0; k < W; k++) sum += PCNT[t * W + k];
  ts[t] = sum;
  __syncthreads();
  if (t == 0) {
    uint32_t run = 0;
    for (int k = 0; k < TPB; k++) { uint32_t v = ts[k]; ts[k] = run; run += v; }
    s_cnt = (int)run;
    CTL[FC_CNT] = (int)run;
  }
  __syncthreads();
  uint32_t run = ts[t];
  for (int k = 0; k < W; k++) { int w = t * W + k; WOFF[w] = run; run += PCNT[w]; }
  int cnt = s_cnt;
  int cnw = (cnt + 63) >> 6;
  for (int w = t; w < cnw; w += TPB) {
    int rem = cnt - (w << 6);
    UNCLC[w] = (rem >= 64) ? ~0ull : ((1ull << rem) - 1ull);
  }
}

__global__ void pre3_fat(const float* __restrict__ pred, char* __restrict__ ws) {
  uint64_t* MASKW = (uint64_t*)(ws + F_MASK);
  uint32_t* WOFF = (uint32_t*)(ws + F_WOFF);
  int* CIDX = (int*)(ws + F_CIDX);
  float2* CEXY = (float2*)(ws + F_CEXY);
  float* CSM = (float*)(ws + F_CSM);
  float* CSV = (float*)(ws + F_CSV);
  float* CSX = (float*)(ws + F_CSX);
  float* CSY = (float*)(ws + F_CSY);
  int gid = blockIdx.x * blockDim.x + threadIdx.x;
  int stride = gridDim.x * blockDim.x;
  int lane = threadIdx.x & 63;
  for (int i = gid; i < NPIX; i += stride) {
    int w = i >> 6;
    uint64_t mw = MASKW[w];
    if ((mw >> lane) & 1ull) {
      int dst = (int)WOFF[w] + (int)__popcll(mw & ((1ull << lane) - 1ull));
      if (dst < CMAX) {
        CIDX[dst] = i;
        float ex, ey; compute_emb(pred, i, ex, ey);
        CEXY[dst] = make_float2(ex, ey);
        CSM[dst] = compute_sm(pred, i);
        CSV[dst] = 1.0f / (1.0f + expf(-pred[(size_t)4 * NPIX + i]));
        CSX[dst] = expf(pred[(size_t)2 * NPIX + i] * 10.0f);
        CSY[dst] = expf(pred[(size_t)3 * NPIX + i] * 10.0f);
      }
    }
  }
}

// ======================= FAT path: main loop =======================
__global__ __launch_bounds__(TPB) void cluster_fat(const float* __restrict__ pred,
                                                   int* __restrict__ out,
                                                   char* __restrict__ ws, int nblk) {
  uint64_t* UNCLC = (uint64_t*)(ws + F_UNCL);
  uint64_t* P1C = (uint64_t*)(ws + F_P1);
  uint64_t* PV = (uint64_t*)(ws + F_PV);
  uint64_t* PSA = (uint64_t*)(ws + F_PSA);
  uint64_t* PSB = (uint64_t*)(ws + F_PSB);
  int* CTL = (int*)(ws + F_CTL);
  const int* __restrict__ CIDX = (const int*)(ws + F_CIDX);
  const float2* __restrict__ CEXY = (const float2*)(ws + F_CEXY);
  const float* __restrict__ CSM = (const float*)(ws + F_CSM);
  const float* __restrict__ CSV = (const float*)(ws + F_CSV);
  const float* __restrict__ CSX = (const float*)(ws + F_CSX);
  const float* __restrict__ CSY = (const float*)(ws + F_CSY);

  const int tid = threadIdx.x;
  const int lane = tid & 63;
  const int bid = blockIdx.x;
  const int nw = nblk * (TPB / 64);
  const int gw0 = bid * (TPB / 64) + (tid >> 6);
  const int cnt = al(&CTL[FC_CNT]);
  const int cnw = (cnt + 63) >> 6;

  __shared__ uint64_t lK[TPB / 64], lA[TPB / 64], lB[TPB / 64];
  __shared__ int lbin[256];
  __shared__ float s_cx[MAXI], s_cy[MAXI], s_sx[MAXI], s_sy[MAXI];
  __shared__ int s_sz[MAXI];

  int ph = 0;

  // ---- pass A0: Sall = cnt (uncl all ones), argmax(CSM) ----
  {
    int par = (ph + 1) & 1;
    uint64_t key = 0, sa = 0, sb = 0;
    for (int w = gw0; w < cnw; w += nw) {
      int j = (w << 6) | lane;
      if (j < cnt) {
        sa++;
        float v = CSM[j];
        uint64_t k2 = ((uint64_t)(uint32_t)__float_as_int(v) << 32) | (uint32_t)~(uint32_t)j;
        if (k2 > key) key = k2;
      }
    }
    bred(key, sa, sb, lK, lA, lB);
    if (tid == 0) {
      as64(&PV[par * NBLK_FAT + bid], key);
      as64(&PSA[par * NBLK_FAT + bid], sa);
      as64(&PSB[par * NBLK_FAT + bid], sb);
    }
  }
  gbar_d(CTL, nblk, ++ph);
  float val1; int seed1; int Sall;
  {
    int par = ph & 1;
    uint64_t key, sa, sb;
    gred(PV + par * NBLK_FAT, PSA + par * NBLK_FAT, PSB + par * NBLK_FAT, nblk,
         key, sa, sb, lK, lA, lB);
    val1 = __int_as_float((int)(key >> 32));
    seed1 = (int)~(uint32_t)key;
    Sall = (int)sa;
  }
  float cx1, cy1, sx1, sy1;
  {
    int j = (seed1 >= 0 && seed1 < cnt) ? seed1 : 0;
    float2 e = CEXY[j]; cx1 = e.x; cy1 = e.y; sx1 = CSX[j]; sy1 = CSY[j];
  }

  int count = 1, it = 0;
  while (Sall > 160 && count < 200 && it < 2000) {
    if (val1 < 0.5f) break;   // 'stop': freeze state

    // ---- pass B: prop1 bits, cnt1, seed2 = argmax(CSV | prop1) ----
    {
      int par = (ph + 1) & 1;
      uint64_t key = 0, sa = 0, sb = 0;
      for (int w0 = gw0; w0 < cnw; w0 += nw * UNROLL) {
#pragma unroll
        for (int u = 0; u < UNROLL; u++) {
          int w = w0 + u * nw;
          if (w >= cnw) continue;
          int j = (w << 6) | lane;
          bool p = false;
          if (j < cnt) {
            float2 e = CEXY[j];
            p = prop_test(e.x, e.y, cx1, cy1, sx1, sy1);
          }
          uint64_t r = __ballot(p);
          if (lane == 0) P1C[w] = r;   // plain: wave-private
          if (p) {
            sa++;
            float v = CSV[j];
            uint64_t k2 = ((uint64_t)(uint32_t)__float_as_int(v) << 32) | (uint32_t)~(uint32_t)j;
            if (k2 > key) key = k2;
          }
        }
      }
      bred(key, sa, sb, lK, lA, lB);
      if (tid == 0) {
        as64(&PV[par * NBLK_FAT + bid], key);
        as64(&PSA[par * NBLK_FAT + bid], sa);
        as64(&PSB[par * NBLK_FAT + bid], sb);
      }
    }
    gbar_d(CTL, nblk, ++ph);
    int seed2, cnt1;
    {
      int par = ph & 1;
      uint64_t key, sa, sb;
      gred(PV + par * NBLK_FAT, PSA + par * NBLK_FAT, PSB + par * NBLK_FAT, nblk,
           key, sa, sb, lK, lA, lB);
      seed2 = (int)~(uint32_t)key;
      cnt1 = (int)sa;
    }
    bool big1 = cnt1 > 160;
    float cx2, cy2, sx2, sy2;
    {
      // seed2 garbage only when cnt1==0 -> big1 false -> prop2 never affects state
      int j = (seed2 >= 0 && seed2 < cnt) ? seed2 : 0;
      float2 e = CEXY[j]; cx2 = e.x; cy2 = e.y; sx2 = CSX[j]; sy2 = CSY[j];
    }

    // ---- pass C (fused): prop2 counts/overlap + flags + uncl update + next argmax ----
    {
      int par = (ph + 1) & 1;
      uint64_t key = 0, sa = 0, sb = 0;
      for (int w0 = gw0; w0 < cnw; w0 += nw * UNROLL) {
#pragma unroll
        for (int u = 0; u < UNROLL; u++) {
          int w = w0 + u * nw;
          if (w >= cnw) continue;
          uint64_t uw = UNCLC[w];                  // plain: wave-private
          uint64_t p1w = big1 ? 0ull : P1C[w];
          int j = (w << 6) | lane;
          bool p = false;
          if (j < cnt) {
            float2 e = CEXY[j];
            p = prop_test(e.x, e.y, cx2, cy2, sx2, sy2);
          }
          bool ub = ((uw >> lane) & 1ull) != 0;
          if (p) sa += ub ? 0x100000001ull : 1ull;   // c2 | ov<<32
          // seed-clear corrections (reference clears uncl at seed1/seed2 pre-overlap)
          if (j == seed1) as_(&CTL[FC_FLG1], p ? 1 : 0);
          if (j == seed2) as_(&CTL[FC_FLG2], (p && ub) ? 1 : 0);
          bool fp = big1 ? p : (((p1w >> lane) & 1ull) != 0);
          bool nu = ub && !(fp || j == seed1 || (big1 && j == seed2));
          uint64_t r = __ballot(nu);
          if (lane == 0 && uw) UNCLC[w] = r;       // plain: wave-private
          if (nu) {
            sb++;
            float v = CSM[j];
            uint64_t k2 = ((uint64_t)(uint32_t)__float_as_int(v) << 32) | (uint32_t)~(uint32_t)j;
            if (k2 > key) key = k2;
          }
        }
      }
      bred(key, sa, sb, lK, lA, lB);
      if (tid == 0) {
        as64(&PV[par * NBLK_FAT + bid], key);
        as64(&PSA[par * NBLK_FAT + bid], sa);
        as64(&PSB[par * NBLK_FAT + bid], sb);
      }
    }
    gbar_d(CTL, nblk, ++ph);
    {
      int par = ph & 1;
      uint64_t key, sa, sb;
      gred(PV + par * NBLK_FAT, PSA + par * NBLK_FAT, PSB + par * NBLK_FAT, nblk,
           key, sa, sb, lK, lA, lB);
      int cnt2 = (int)(uint32_t)sa;
      int ovl = (int)(uint32_t)(sa >> 32);
      ovl -= al(&CTL[FC_FLG1]);
      if (big1 && seed2 != seed1) ovl -= al(&CTL[FC_FLG2]);
      bool big2 = cnt2 > 160;
      int den = cnt2 > 1 ? cnt2 : 1;
      float ratio = (float)ovl / (float)den;
      bool accept = big1 && big2 && (ratio > 0.5f);
      if (accept) {
        if (tid == 0) {
          s_cx[count] = cx2; s_cy[count] = cy2;
          s_sx[count] = sx2; s_sy[count] = sy2;
          s_sz[count] = cnt2;
        }
        count++;
      }
      it++;
      val1 = __int_as_float((int)(key >> 32));
      seed1 = (int)~(uint32_t)key;
      Sall = (int)sb;
    }
    {
      int j = (seed1 >= 0 && seed1 < cnt) ? seed1 : 0;
      float2 e = CEXY[j]; cx1 = e.x; cy1 = e.y; sx1 = CSX[j]; sy1 = CSY[j];
    }
  }

  // ---- reconstruction: out = last accepted instance containing pixel; bincount ----
  lbin[tid] = 0;
  __syncthreads();   // publishes tid0's s_* log writes block-wide
  for (int w = gw0; w < cnw; w += nw) {
    int j = (w << 6) | lane;
    if (j < cnt) {
      float2 e = CEXY[j];
      int id = 0;
      for (int k = 1; k < count; k++)
        if (prop_test(e.x, e.y, s_cx[k], s_cy[k], s_sx[k], s_sy[k])) id = k;
      out[CIDX[j]] = id;   // plain: re-read by same wave below
      atomicAdd(&lbin[id], 1);
    }
  }
  __syncthreads();
  if (lbin[tid] > 0)
    __hip_atomic_fetch_add(&CTL[FC_NOW + tid], lbin[tid], __ATOMIC_RELAXED,
                           __HIP_MEMORY_SCOPE_AGENT);
  gbar_d(CTL, nblk, ++ph);
  lbin[tid] = al(&CTL[FC_NOW + tid]);
  __syncthreads();
  for (int w = gw0; w < cnw; w += nw) {
    int j = (w << 6) | lane;
    if (j < cnt) {
      int i = CIDX[j];
      int id = out[i];
      if (id > 0) {
        int n = lbin[id];
        int sz = s_sz[id];
        bool rm = (n != sz) && ((n < 480) || ((float)n < 0.5f * (float)sz));
        if (rm) out[i] = 0;
      }
    }
  }
}

// ======================= THIN fallback (round-5, proven) =======================
__device__ __forceinline__ void gbar_rel(int* CTL, int nblk, int ph) {
  __syncthreads();
  if (threadIdx.x == 0) {
    asm volatile("s_waitcnt vmcnt(0)" ::: "memory");
    as_(&CTL[blockIdx.x * 32], ph);
  }
  if (blockIdx.x == 0) {
    if (threadIdx.x < 64) {
      for (;;) {
        bool ok = true;
        for (int b = (int)threadIdx.x; b < nblk; b += 64)
          ok &= (al(&CTL[b * 32]) >= ph);
        if (__all(ok)) break;
        __builtin_amdgcn_s_sleep(1);
      }
      asm volatile("" ::: "memory");
      if (threadIdx.x == 0) as_(&CTL[TC_REL], ph);
    }
  } else {
    if (threadIdx.x == 0) {
      while (al(&CTL[TC_REL]) < ph) __builtin_amdgcn_s_sleep(1);
      asm volatile("" ::: "memory");
    }
  }
  __syncthreads();
}

__global__ void precompute_thin(const float* __restrict__ pred, int* __restrict__ out,
                                char* __restrict__ ws) {
  uint64_t* MASKW = (uint64_t*)(ws + T_MASK);
  uint64_t* UNCLW = (uint64_t*)(ws + T_UNCL);
  int* CTL = (int*)(ws + T_CTL);
  int gid = blockIdx.x * blockDim.x + threadIdx.x;
  int stride = gridDim.x * blockDim.x;
  for (int i = gid; i < NPIX; i += stride) {
    float smv = compute_sm(pred, i);
    unsigned long long bal = __ballot(smv > 0.5f);
    if ((threadIdx.x & 63) == 0) { MASKW[i >> 6] = bal; UNCLW[i >> 6] = bal; }
    out[i] = 0;
  }
  if (gid < TC_ZEND) CTL[gid] = 0;
}

__global__ __launch_bounds__(TPB) void cluster_thin(const float* __restrict__ pred,
                                                    int* __restrict__ out,
                                                    char* __restrict__ ws, int nblk) {
  uint64_t* MASKW = (uint64_t*)(ws + T_MASK);
  uint64_t* UNCLW = (uint64_t*)(ws + T_UNCL);
  uint64_t* P1W = (uint64_t*)(ws + T_P1);
  uint64_t* PV = (uint64_t*)(ws + T_PV);
  uint64_t* PSA = (uint64_t*)(ws + T_PSA);
  uint64_t* PSB = (uint64_t*)(ws + T_PSB);
  int* CTL = (int*)(ws + T_CTL);

  const int tid = threadIdx.x;
  const int lane = tid & 63;
  const int bid = blockIdx.x;
  const int nw = nblk * (TPB / 64);
  const int gw0 = bid * (TPB / 64) + (tid >> 6);

  __shared__ uint64_t lK[TPB / 64], lA[TPB / 64], lB[TPB / 64];
  __shared__ int lbin[256];
  __shared__ float s_cx[MAXI], s_cy[MAXI], s_sx[MAXI], s_sy[MAXI];
  __shared__ int s_sz[MAXI];

  int ph = 0;
  {
    int par = (ph + 1) & 1;
    uint64_t key = 0, sa = 0, sb = 0;
    for (int w = gw0; w < NWORD; w += nw) {
      uint64_t uw = UNCLW[w];
      if (!uw) continue;
      int i = (w << 6) | lane;
      if ((uw >> lane) & 1ull) {
        sa++;
        float v = compute_sm(pred, i);
        uint64_t k2 = ((uint64_t)(uint32_t)__float_as_int(v) << 32) | (uint32_t)~(uint32_t)i;
        if (k2 > key) key = k2;
      }
    }
    bred(key, sa, sb, lK, lA, lB);
    if (tid == 0) {
      as64(&PV[par * T_NBLK + bid], key);
      as64(&PSA[par * T_NBLK + bid], sa);
      as64(&PSB[par * T_NBLK + bid], sb);
    }
  }
  gbar_rel(CTL, nblk, ++ph);
  float val1; int seed1; int Sall;
  {
    int par = ph & 1;
    uint64_t key, sa, sb;
    gred(PV + par * T_NBLK, PSA + par * T_NBLK, PSB + par * T_NBLK, nblk, key, sa, sb, lK, lA, lB);
    val1 = __int_as_float((int)(key >> 32));
    seed1 = (int)~(uint32_t)key;
    Sall = (int)sa;
  }
  float cx1, cy1, sx1, sy1;
  {
    int bj = (seed1 >= 0 && seed1 < NPIX) ? seed1 : 0;
    compute_emb(pred, bj, cx1, cy1);
    sx1 = expf(pred[(size_t)2 * NPIX + bj] * 10.0f);
    sy1 = expf(pred[(size_t)3 * NPIX + bj] * 10.0f);
  }

  int count = 1, it = 0;
  while (Sall > 160 && count < 200 && it < 2000) {
    if (val1 < 0.5f) break;
    {
      int par = (ph + 1) & 1;
      uint64_t key = 0, sa = 0, sb = 0;
      for (int w = gw0; w < NWORD; w += nw) {
        uint64_t mw = MASKW[w];
        if (!mw) continue;
        int i = (w << 6) | lane;
        bool p = false;
        if ((mw >> lane) & 1ull) {
          float ex, ey; compute_emb(pred, i, ex, ey);
          p = prop_test(ex, ey, cx1, cy1, sx1, sy1);
        }
        uint64_t r = __ballot(p);
        if (lane == 0) P1W[w] = r;
        if (p) {
          sa++;
          float v = 1.0f / (1.0f + expf(-pred[(size_t)4 * NPIX + i]));
          uint64_t k2 = ((uint64_t)(uint32_t)__float_as_int(v) << 32) | (uint32_t)~(uint32_t)i;
          if (k2 > key) key = k2;
        }
      }
      bred(key, sa, sb, lK, lA, lB);
      if (tid == 0) {
        as64(&PV[par * T_NBLK + bid], key);
        as64(&PSA[par * T_NBLK + bid], sa);
        as64(&PSB[par * T_NBLK + bid], sb);
      }
    }
    gbar_rel(CTL, nblk, ++ph);
    int seed2, cnt1;
    {
      int par = ph & 1;
      uint64_t key, sa, sb;
      gred(PV + par * T_NBLK, PSA + par * T_NBLK, PSB + par * T_NBLK, nblk, key, sa, sb, lK, lA, lB);
      seed2 = (int)~(uint32_t)key;
      cnt1 = (int)sa;
    }
    bool big1 = cnt1 > 160;
    float cx2, cy2, sx2, sy2;
    {
      int bj = (seed2 >= 0 && seed2 < NPIX) ? seed2 : 0;
      compute_emb(pred, bj, cx2, cy2);
      sx2 = expf(pred[(size_t)2 * NPIX + bj] * 10.0f);
      sy2 = expf(pred[(size_t)3 * NPIX + bj] * 10.0f);
    }
    {
      int par = (ph + 1) & 1;
      uint64_t key = 0, sa = 0, sb = 0;
      for (int w = gw0; w < NWORD; w += nw) {
        uint64_t mw = MASKW[w];
        if (!mw) continue;
        uint64_t uw = UNCLW[w];
        uint64_t p1w = big1 ? 0ull : P1W[w];
        int i = (w << 6) | lane;
        bool p = false;
        if ((mw >> lane) & 1ull) {
          float ex, ey; compute_emb(pred, i, ex, ey);
          p = prop_test(ex, ey, cx2, cy2, sx2, sy2);
        }
        bool ub = ((uw >> lane) & 1ull) != 0;
        if (p) sa += ub ? 0x100000001ull : 1ull;
        if (i == seed1) as_(&CTL[TC_FLG1], p ? 1 : 0);
        if (i == seed2) as_(&CTL[TC_FLG2], (p && ub) ? 1 : 0);
        bool fp = big1 ? p : (((p1w >> lane) & 1ull) != 0);
        bool nu = ub && !(fp || i == seed1 || (big1 && i == seed2));
        uint64_t r = __ballot(nu);
        if (lane == 0 && uw) UNCLW[w] = r;
        if (nu) {
          sb++;
          float v = compute_sm(pred, i);
          uint64_t k2 = ((uint64_t)(uint32_t)__float_as_int(v) << 32) | (uint32_t)~(uint32_t)i;
          if (k2 > key) key = k2;
        }
      }
      bred(key, sa, sb, lK, lA, lB);
      if (tid == 0) {
        as64(&PV[par * T_NBLK + bid], key);
        as64(&PSA[par * T_NBLK + bid], sa);
        as64(&PSB[par * T_NBLK + bid], sb);
      }
    }
    gbar_rel(CTL, nblk, ++ph);
    {
      int par = ph & 1;
      uint64_t key, sa, sb;
      gred(PV + par * T_NBLK, PSA + par * T_NBLK, PSB + par * T_NBLK, nblk, key, sa, sb, lK, lA, lB);
      int cnt2 = (int)(uint32_t)sa;
      int ovl = (int)(uint32_t)(sa >> 32);
      ovl -= al(&CTL[TC_FLG1]);
      if (big1 && seed2 != seed1) ovl -= al(&CTL[TC_FLG2]);
      bool big2 = cnt2 > 160;
      int den = cnt2 > 1 ? cnt2 : 1;
      float ratio = (float)ovl / (float)den;
      bool accept = big1 && big2 && (ratio > 0.5f);
      if (accept) {
        if (tid == 0) {
          s_cx[count] = cx2; s_cy[count] = cy2;
          s_sx[count] = sx2; s_sy[count] = sy2;
          s_sz[count] = cnt2;
        }
        count++;
      }
      it++;
      val1 = __int_as_float((int)(key >> 32));
      seed1 = (int)~(uint32_t)key;
      Sall = (int)sb;
    }
    {
      int bj = (seed1 >= 0 && seed1 < NPIX) ? seed1 : 0;
      compute_emb(pred, bj, cx1, cy1);
      sx1 = expf(pred[(size_t)2 * NPIX + bj] * 10.0f);
      sy1 = expf(pred[(size_t)3 * NPIX + bj] * 10.0f);
    }
  }

  lbin[tid] = 0;
  __syncthreads();
  for (int w = gw0; w < NWORD; w += nw) {
    uint64_t mw = MASKW[w];
    int i = (w << 6) | lane;
    int id = 0;
    if ((mw >> lane) & 1ull) {
      float ex, ey; compute_emb(pred, i, ex, ey);
      for (int k = 1; k < count; k++)
        if (prop_test(ex, ey, s_cx[k], s_cy[k], s_sx[k], s_sy[k])) id = k;
    }
    out[i] = id;
    atomicAdd(&lbin[id], 1);
  }
  __syncthreads();
  if (lbin[tid] > 0)
    __hip_atomic_fetch_add(&CTL[TC_NOW + tid], lbin[tid], __ATOMIC_RELAXED,
                           __HIP_MEMORY_SCOPE_AGENT);
  gbar_rel(CTL, nblk, ++ph);
  lbin[tid] = al(&CTL[TC_NOW + tid]);
  __syncthreads();
  for (int w = gw0; w < NWORD; w += nw) {
    int i = (w << 6) | lane;
    int id = out[i];
    if (id > 0) {
      int n = lbin[id];
      int sz = s_sz[id];
      bool rm = (n != sz) && ((n < 480) || ((float)n < 0.5f * (float)sz));
      if (rm) out[i] = 0;
    }
  }
}

extern "C" void kernel_launch(void* const* d_in, const int* in_sizes, int n_in,
                              void* d_out, int out_size, void* d_ws, size_t ws_size,
                              hipStream_t stream) {
  const float* pred = (const float*)d_in[0];
  int* out = (int*)d_out;
  char* ws = (char*)d_ws;

  int dev = 0;
  hipGetDevice(&dev);
  int numCU = 0;
  hipDeviceGetAttribute(&numCU, hipDeviceAttributeMultiprocessorCount, dev);
  if (numCU <= 0) numCU = 256;

  if (ws_size >= FAT_NEED) {
    hipLaunchKernelGGL(pre1_fat, dim3(4096), dim3(TPB), 0, stream, pred, out, ws);
    hipLaunchKernelGGL(pre2_fat, dim3(1), dim3(TPB), 0, stream, ws);
    hipLaunchKernelGGL(pre3_fat, dim3(4096), dim3(TPB), 0, stream, pred, ws);
    int nblk = NBLK_FAT;
    int maxPerCU = 0;
    if (hipOccupancyMaxActiveBlocksPerMultiprocessor(&maxPerCU, (const void*)cluster_fat,
                                                     TPB, 0) == hipSuccess && maxPerCU > 0) {
      long long cap = (long long)maxPerCU * numCU;
      if (cap < nblk) nblk = (int)cap;
    }
    if (nblk < 1) nblk = 1;
    void* args[] = {(void*)&pred, (void*)&out, (void*)&ws, (void*)&nblk};
    hipLaunchCooperativeKernel((void*)cluster_fat, dim3(nblk), dim3(TPB), args, 0, stream);
  } else {
    hipLaunchKernelGGL(precompute_thin, dim3(4096), dim3(TPB), 0, stream, pred, out, ws);
    int nblk = T_NBLK;
    int maxPerCU = 0;
    if (hipOccupancyMaxActiveBlocksPerMultiprocessor(&maxPerCU, (const void*)cluster_thin,
                                                     TPB, 0) == hipSuccess && maxPerCU > 0) {
      long long cap = (long long)maxPerCU * numCU;
      if (cap < nblk) nblk = (int)cap;
    }
    if (nblk < 1) nblk = 1;
    void* args[] = {(void*)&pred, (void*)&out, (void*)&ws, (void*)&nblk};
    hipLaunchCooperativeKernel((void*)cluster_thin, dim3(nblk), dim3(TPB), args, 0, stream);
  }
}